// Round 5
// baseline (3480.467 us; speedup 1.0000x reference)
//
#include <hip/hip_runtime.h>
#include <math.h>

// ---------------------------------------------------------------------------
// Problem constants (PatchTST-style transformer)
// ---------------------------------------------------------------------------
namespace {
constexpr int kB = 32, kT = 512, kC = 32, kD = 512, kDFF = 2048, kNL = 3;
constexpr int kP = 16, kStride = 8, kN = 64;
constexpr int kR = kB * kC;      // 1024 independent (b,c) series
constexpr int kM = kR * kN;      // 65536 tokens total
constexpr size_t kWbElems = (size_t)1536 * 512 + 512 * 512 + 2048 * 512 + 512 * 2048;
}

typedef unsigned short u16;
typedef __attribute__((ext_vector_type(8))) short short8;   // 8 bf16 (4 VGPRs)
typedef __attribute__((ext_vector_type(4))) float f32x4;    // MFMA accumulator

__device__ __forceinline__ float b2f(u16 u) {
    return __uint_as_float(((unsigned int)u) << 16);
}
__device__ __forceinline__ u16 f2b(float f) {
    unsigned int x = __float_as_uint(f);
    return (u16)((x + 0x7fffu + ((x >> 16) & 1u)) >> 16);
}

// async global->LDS, 16B per lane (builtin: IR-visible, __syncthreads-safe).
__device__ __forceinline__ void async_copy16(const u16* g, u16* l) {
    __builtin_amdgcn_global_load_lds(
        (const __attribute__((address_space(1))) unsigned int*)g,
        (__attribute__((address_space(3))) unsigned int*)l, 16, 0, 0);
}

// ---------------------------------------------------------------------------
// Sentinel fill (workspace-too-small diagnostic)
// ---------------------------------------------------------------------------
__global__ void fill_kernel(float* __restrict__ p, float val, int n)
{
    int i = blockIdx.x * blockDim.x + threadIdx.x;
    if (i < n) p[i] = val;
}

// ---------------------------------------------------------------------------
// Instance-norm stats per (b,c)
// ---------------------------------------------------------------------------
__global__ __launch_bounds__(256) void instnorm_stats_kernel(
    const float* __restrict__ x, float* __restrict__ means, float* __restrict__ stdev)
{
    int b = blockIdx.x;
    int c = threadIdx.x & 31;
    int g = threadIdx.x >> 5;
    float s = 0.f, sq = 0.f;
    for (int t = g; t < kT; t += 8) {
        float v = x[(size_t)(b * kT + t) * kC + c];
        s += v; sq += v * v;
    }
    __shared__ float ss[8][32], ssq[8][32];
    ss[g][c] = s; ssq[g][c] = sq;
    __syncthreads();
    if (g == 0) {
        float S = 0.f, SQ = 0.f;
        for (int i = 0; i < 8; i++) { S += ss[i][c]; SQ += ssq[i][c]; }
        float m = S / kT;
        float var = SQ / kT - m * m;
        means[b * kC + c] = m;
        stdev[b * kC + c] = sqrtf(var + 1e-5f);
    }
}

// ---------------------------------------------------------------------------
// Patch embed (bf16 out)
// ---------------------------------------------------------------------------
__global__ __launch_bounds__(256) void patch_embed_kernel(
    const float* __restrict__ x, const float* __restrict__ Wval,
    const float* __restrict__ means, const float* __restrict__ stdev,
    u16* __restrict__ tok)
{
    int m = blockIdx.x;
    int r = m >> 6, n = m & 63;
    int b = r >> 5, c = r & 31;
    __shared__ float patch[kP];
    if (threadIdx.x < kP) {
        int t = n * kStride + threadIdx.x;
        if (t > kT - 1) t = kT - 1;
        patch[threadIdx.x] = (x[(size_t)(b * kT + t) * kC + c] - means[r]) / stdev[r];
    }
    __syncthreads();
    for (int d = threadIdx.x; d < kD; d += 256) {
        float acc = 0.f;
        #pragma unroll
        for (int p = 0; p < kP; p++) acc += patch[p] * Wval[p * kD + d];
        int j = d >> 1;
        float freq = expf(-(float)(2 * j) * (9.210340371976184f / (float)kD));
        float ang = (float)n * freq;
        float pe = (d & 1) ? cosf(ang) : sinf(ang);
        tok[(size_t)m * kD + d] = f2b(acc + pe);
    }
}

// ---------------------------------------------------------------------------
// Transpose + fp32->bf16 convert: out[n*ldo + k] = f2b(in[k*ldi + n])
// per z-slice: in += z*zin, out += z*zout.  grid (K/64, N/64, Z), 256 thr.
// ---------------------------------------------------------------------------
__global__ __launch_bounds__(256) void transpose_cvt_kernel(
    const float* __restrict__ in, u16* __restrict__ outp,
    int ldi, int ldo, int zin, int zout)
{
    __shared__ float tile[64][65];
    const float* ib = in + (size_t)blockIdx.z * zin;
    u16* ob = outp + (size_t)blockIdx.z * zout;
    int k0 = blockIdx.x * 64, n0 = blockIdx.y * 64;
    int tn = threadIdx.x & 63, tk0 = threadIdx.x >> 6;
    #pragma unroll
    for (int kk = tk0; kk < 64; kk += 4)
        tile[kk][tn] = ib[(size_t)(k0 + kk) * ldi + n0 + tn];
    __syncthreads();
    int wk = threadIdx.x & 63, wn0 = threadIdx.x >> 6;
    #pragma unroll
    for (int nn = wn0; nn < 64; nn += 4)
        ob[(size_t)(n0 + nn) * ldo + k0 + wk] = f2b(tile[wk][nn]);
}

// ---------------------------------------------------------------------------
// MFMA bf16 GEMM, 128x128 tile, BK=64, 256 thr (4 waves 2x2), m97 structure
// (2x __syncthreads per K-step; compiler-managed waits; multi-block-per-CU
// overlap hides the barrier drain — m114).  REVERT from the 256x256 8-phase
// experiments (R1-R4: three staging mechanisms all stuck at MfmaUtil 5.5%).
//
// LDS 32 KiB: As/Bs [128 rows][64 cols] with chunk-XOR swizzle: 16B phys
// chunk p of row r holds logical chunk p^(r&7) (BK=64 -> 128B rows -> 8
// chunks; conflict-free ds_read_b128, verified 0 conflicts in R2 at BK=64;
// R0's BK=32 variant was structurally 4-way-conflicted, 4.19M/dispatch).
// Staging pre-swizzles the GLOBAL source chunk per lane (DMA dest linear).
//
// A: [M][lda] bf16 row-major.  B: [N][ldb] bf16 N-MAJOR (row n = output col).
// grid: (N/128, M/128, Z) — Z>1 = split-K (global k = z*K + kb), EPI 3 only.
// EPI 0: qkv — dst/bias by 512-col group: C0/C1/C2, bias/auxb1/auxb2
// EPI 1: C0[r*ldc+c] += acc + (bias?bias[c]:0)       (bf16 rmw)
// EPI 2: C0[r*ldc+c]  = gelu_erf(acc + bias[c])
// EPI 3: atomicAdd(fout[((r>>5)*512+c)*32 + (r&31)], acc*stdev[r])
// ---------------------------------------------------------------------------
template<int EPI>
__global__ __launch_bounds__(256) void mfma_gemm(
    const u16* __restrict__ A, const u16* __restrict__ B,
    const float* __restrict__ bias, const float* __restrict__ auxb1,
    const float* __restrict__ auxb2,
    u16* __restrict__ C0, u16* __restrict__ C1, u16* __restrict__ C2,
    float* __restrict__ fout, const float* __restrict__ stdev,
    int K, int lda, int ldb, int ldc)
{
    __shared__ alignas(16) u16 As[128 * 64];   // 16 KiB
    __shared__ alignas(16) u16 Bs[128 * 64];   // 16 KiB

    const int tid  = threadIdx.x;
    const int lane = tid & 63;
    const int wave = tid >> 6;
    const int wm   = wave >> 1;        // 0..1
    const int wn   = wave & 1;         // 0..1

    // bijective XCD swizzle (m204) over the (x,y) grid plane: consecutive
    // blocks (same A row-stripe, different col-block) land on one XCD -> the
    // A-stripe is fetched once per XCD L2 instead of once per block.
    const int nwg  = gridDim.x * gridDim.y;
    const int orig = blockIdx.y * gridDim.x + blockIdx.x;
    const int qq = nwg >> 3, rr = nwg & 7;
    const int xcd = orig & 7, loc = orig >> 3;
    const int wg  = (xcd < rr) ? (xcd * (qq + 1) + loc)
                               : (rr * (qq + 1) + (xcd - rr) * qq + loc);
    const int row0 = (wg / gridDim.x) * 128;
    const int col0 = (wg % gridDim.x) * 128;
    const size_t zoff = (size_t)blockIdx.z * K;

    // staging: 8 lanes/row (8x16B = 128B row), 32 rows per async round,
    // 4 rounds per matrix.  Lane fetches logical chunk (tid&7)^(srow&7) so
    // the linear DMA dest (base + tid*16B) yields phys chunk p = q^(r&7).
    const int srow = tid >> 3;                         // 0..31
    const int scol = (((tid & 7) ^ (srow & 7)) << 3);
    const u16* const Ag = A + (size_t)(row0 + srow) * lda + zoff + scol;
    const u16* const Bg = B + (size_t)(col0 + srow) * ldb + zoff + scol;
    u16* const AsW = As + (wave << 9);   // this wave's 8-row piece per round
    u16* const BsW = Bs + (wave << 9);

    // fragment reads: logical chunk q (=lane>>4 for k-half 0; ^4 for half 1)
    // of row r sits at phys q^(r&7); r&7 == lane&7 within each 16-row group.
    const int fr = lane & 15;
    const int pc = (lane >> 4) ^ (lane & 7);
    const int a0 = ((wm << 6) + fr) * 64 + (pc << 3);
    const int a1 = ((wm << 6) + fr) * 64 + ((pc ^ 4) << 3);
    const int b0 = ((wn << 6) + fr) * 64 + (pc << 3);
    const int b1 = ((wn << 6) + fr) * 64 + ((pc ^ 4) << 3);

    short8 af[4], bfr[4];
    f32x4 acc[4][4];
    #pragma unroll
    for (int i = 0; i < 4; i++)
        #pragma unroll
        for (int j = 0; j < 4; j++)
            acc[i][j] = (f32x4){0.f, 0.f, 0.f, 0.f};

    for (int kb = 0; kb < K; kb += 64) {
        __syncthreads();
        #pragma unroll
        for (int c = 0; c < 4; c++) {
            async_copy16(Ag + kb + (size_t)(c * 32) * lda, AsW + c * 2048);
            async_copy16(Bg + kb + (size_t)(c * 32) * ldb, BsW + c * 2048);
        }
        __syncthreads();
        // k-half 0
        #pragma unroll
        for (int mi = 0; mi < 4; mi++) af[mi]  = *(const short8*)&As[a0 + (mi << 10)];
        #pragma unroll
        for (int ni = 0; ni < 4; ni++) bfr[ni] = *(const short8*)&Bs[b0 + (ni << 10)];
        #pragma unroll
        for (int mi = 0; mi < 4; mi++)
            #pragma unroll
            for (int ni = 0; ni < 4; ni++)
                acc[mi][ni] = __builtin_amdgcn_mfma_f32_16x16x32_bf16(
                    af[mi], bfr[ni], acc[mi][ni], 0, 0, 0);
        // k-half 1
        #pragma unroll
        for (int mi = 0; mi < 4; mi++) af[mi]  = *(const short8*)&As[a1 + (mi << 10)];
        #pragma unroll
        for (int ni = 0; ni < 4; ni++) bfr[ni] = *(const short8*)&Bs[b1 + (ni << 10)];
        #pragma unroll
        for (int mi = 0; mi < 4; mi++)
            #pragma unroll
            for (int ni = 0; ni < 4; ni++)
                acc[mi][ni] = __builtin_amdgcn_mfma_f32_16x16x32_bf16(
                    af[mi], bfr[ni], acc[mi][ni], 0, 0, 0);
    }

    // epilogue: C/D layout col=lane&15, row=(lane>>4)*4+i  [m89-verified]
    const int er = (lane >> 4) << 2;
    const int ec = lane & 15;
    u16* dsel = C0;
    const float* bsel = bias;
    if (EPI == 0) {
        int sub = col0 >> 9;
        dsel = (sub == 0) ? C0 : ((sub == 1) ? C1 : C2);
        bsel = (sub == 0) ? bias : ((sub == 1) ? auxb1 : auxb2);
    }
    #pragma unroll
    for (int mi = 0; mi < 4; mi++) {
        #pragma unroll
        for (int ni = 0; ni < 4; ni++) {
            #pragma unroll
            for (int i = 0; i < 4; i++) {
                int r  = row0 + (wm << 6) + (mi << 4) + er + i;
                int cc = col0 + (wn << 6) + (ni << 4) + ec;
                float v = acc[mi][ni][i];
                if (EPI == 0) {
                    int cl = cc & 511;
                    dsel[(size_t)r * 512 + cl] = f2b(v + bsel[cl]);
                } else if (EPI == 1) {
                    size_t o = (size_t)r * ldc + cc;
                    float bb2 = bias ? bias[cc] : 0.f;
                    C0[o] = f2b(b2f(C0[o]) + v + bb2);
                } else if (EPI == 2) {
                    size_t o = (size_t)r * ldc + cc;
                    float z = v + bias[cc];
                    C0[o] = f2b(0.5f * z * (1.f + erff(z * 0.7071067811865475f)));
                } else {
                    float vv = v * stdev[r];
                    atomicAdd(&fout[(((size_t)(r >> 5) * kT + cc) << 5) + (r & 31)], vv);
                }
            }
        }
    }
}

// ---------------------------------------------------------------------------
// MFMA attention. One block per series; 4 waves; wave w does heads 2w, 2w+1.
// q,k,v: bf16 [rows=64*series][512]; output in place over q.
// ---------------------------------------------------------------------------
__global__ __launch_bounds__(256) void attn_mfma_kernel(
    u16* __restrict__ qbuf, const u16* __restrict__ kbuf,
    const u16* __restrict__ vbuf)
{
    __shared__ u16 P[4][64 * 64];   // 8 KB per wave
    const int tid = threadIdx.x;
    const int wave = tid >> 6, lane = tid & 63;
    const int quad = lane >> 4, l15 = lane & 15;
    const size_t base = (size_t)blockIdx.x * 64 * kD;
    u16* Pw = P[wave];

    for (int hh = 0; hh < 2; hh++) {
        const int h = wave * 2 + hh;
        const u16* qh = qbuf + base + h * 64;
        const u16* kh = kbuf + base + h * 64;
        const u16* vh = vbuf + base + h * 64;

        short8 af[4][2], bf[4][2];
        #pragma unroll
        for (int mi = 0; mi < 4; mi++)
            #pragma unroll
            for (int kt = 0; kt < 2; kt++)
                af[mi][kt] = *(const short8*)(qh + (size_t)(mi * 16 + l15) * kD
                                              + kt * 32 + quad * 8);
        #pragma unroll
        for (int ni = 0; ni < 4; ni++)
            #pragma unroll
            for (int kt = 0; kt < 2; kt++)
                bf[ni][kt] = *(const short8*)(kh + (size_t)(ni * 16 + l15) * kD
                                              + kt * 32 + quad * 8);
        f32x4 S[4][4];
        #pragma unroll
        for (int mi = 0; mi < 4; mi++)
            #pragma unroll
            for (int ni = 0; ni < 4; ni++)
                S[mi][ni] = (f32x4){0.f, 0.f, 0.f, 0.f};
        #pragma unroll
        for (int mi = 0; mi < 4; mi++)
            #pragma unroll
            for (int ni = 0; ni < 4; ni++) {
                S[mi][ni] = __builtin_amdgcn_mfma_f32_16x16x32_bf16(
                    af[mi][0], bf[ni][0], S[mi][ni], 0, 0, 0);
                S[mi][ni] = __builtin_amdgcn_mfma_f32_16x16x32_bf16(
                    af[mi][1], bf[ni][1], S[mi][ni], 0, 0, 0);
            }

        #pragma unroll
        for (int mi = 0; mi < 4; mi++) {
            #pragma unroll
            for (int i = 0; i < 4; i++) {
                float mx = -1e30f;
                #pragma unroll
                for (int ni = 0; ni < 4; ni++) {
                    float v = S[mi][ni][i] * 0.125f;
                    S[mi][ni][i] = v;
                    mx = fmaxf(mx, v);
                }
                #pragma unroll
                for (int off = 1; off < 16; off <<= 1)
                    mx = fmaxf(mx, __shfl_xor(mx, off));
                float sum = 0.f;
                #pragma unroll
                for (int ni = 0; ni < 4; ni++) {
                    float e = expf(S[mi][ni][i] - mx);
                    S[mi][ni][i] = e;
                    sum += e;
                }
                #pragma unroll
                for (int off = 1; off < 16; off <<= 1)
                    sum += __shfl_xor(sum, off);
                float inv = 1.f / sum;
                #pragma unroll
                for (int ni = 0; ni < 4; ni++)
                    Pw[(mi * 16 + quad * 4 + i) * 64 + ni * 16 + l15] =
                        f2b(S[mi][ni][i] * inv);
            }
        }
        __syncthreads();

        short8 bv[4][2];
        #pragma unroll
        for (int ni = 0; ni < 4; ni++)
            #pragma unroll
            for (int kt = 0; kt < 2; kt++)
                #pragma unroll
                for (int j = 0; j < 8; j++)
                    bv[ni][kt][j] = (short)vh[(size_t)(kt * 32 + quad * 8 + j) * kD
                                              + ni * 16 + l15];
        short8 pa[4][2];
        #pragma unroll
        for (int mi = 0; mi < 4; mi++)
            #pragma unroll
            for (int kt = 0; kt < 2; kt++)
                pa[mi][kt] = *(const short8*)&Pw[(mi * 16 + l15) * 64
                                                 + kt * 32 + quad * 8];
        f32x4 O[4][4];
        #pragma unroll
        for (int mi = 0; mi < 4; mi++)
            #pragma unroll
            for (int ni = 0; ni < 4; ni++)
                O[mi][ni] = (f32x4){0.f, 0.f, 0.f, 0.f};
        #pragma unroll
        for (int mi = 0; mi < 4; mi++)
            #pragma unroll
            for (int ni = 0; ni < 4; ni++) {
                O[mi][ni] = __builtin_amdgcn_mfma_f32_16x16x32_bf16(
                    pa[mi][0], bv[ni][0], O[mi][ni], 0, 0, 0);
                O[mi][ni] = __builtin_amdgcn_mfma_f32_16x16x32_bf16(
                    pa[mi][1], bv[ni][1], O[mi][ni], 0, 0, 0);
            }
        u16* qo = qbuf + base + h * 64;
        #pragma unroll
        for (int mi = 0; mi < 4; mi++)
            #pragma unroll
            for (int ni = 0; ni < 4; ni++)
                #pragma unroll
                for (int i = 0; i < 4; i++)
                    qo[(size_t)(mi * 16 + quad * 4 + i) * kD + ni * 16 + l15] =
                        f2b(O[mi][ni][i]);
        __syncthreads();
    }
}

// ---------------------------------------------------------------------------
// Row LayerNorm over D=512, bf16 in/out, in-place safe. 4 rows per block.
// ---------------------------------------------------------------------------
__global__ __launch_bounds__(256) void ln_kernel(
    const u16* __restrict__ x, const float* __restrict__ g,
    const float* __restrict__ bb, u16* __restrict__ y)
{
    size_t row = (size_t)blockIdx.x * 4 + (threadIdx.x >> 6);
    int lane = threadIdx.x & 63;
    float v[8];
    float s = 0.f;
    #pragma unroll
    for (int i = 0; i < 8; i++) {
        v[i] = b2f(x[row * kD + lane + i * 64]);
        s += v[i];
    }
    #pragma unroll
    for (int off = 32; off; off >>= 1) s += __shfl_xor(s, off);
    float mean = s * (1.f / kD);
    float sq = 0.f;
    #pragma unroll
    for (int i = 0; i < 8; i++) { float d = v[i] - mean; sq += d * d; }
    #pragma unroll
    for (int off = 32; off; off >>= 1) sq += __shfl_xor(sq, off);
    float inv = 1.f / sqrtf(sq * (1.f / kD) + 1e-5f);
    #pragma unroll
    for (int i = 0; i < 8; i++) {
        int d = lane + i * 64;
        y[row * kD + d] = f2b((v[i] - mean) * inv * g[d] + bb[d]);
    }
}

// ---------------------------------------------------------------------------
// BatchNorm pieces
// ---------------------------------------------------------------------------
__global__ void zero_kernel(float* __restrict__ p, int n)
{
    int i = blockIdx.x * blockDim.x + threadIdx.x;
    if (i < n) p[i] = 0.f;
}

__global__ __launch_bounds__(512) void bn_stats_kernel(
    const u16* __restrict__ tok, float* __restrict__ sums, float* __restrict__ sumsq)
{
    int d = threadIdx.x;
    float s = 0.f, sq = 0.f;
    int row0 = blockIdx.x * 256;
    for (int row = row0; row < row0 + 256; row++) {
        float v = b2f(tok[(size_t)row * kD + d]);
        s += v; sq += v * v;
    }
    atomicAdd(&sums[d], s);
    atomicAdd(&sumsq[d], sq);
}

__global__ __launch_bounds__(512) void bn_final_kernel(
    const float* __restrict__ sums, const float* __restrict__ sumsq,
    const float* __restrict__ g, const float* __restrict__ bb,
    float* __restrict__ scale, float* __restrict__ shift)
{
    int d = threadIdx.x;
    float mean = sums[d] / (float)kM;
    float var = sumsq[d] / (float)kM - mean * mean;
    float sc = g[d] / sqrtf(var + 1e-5f);
    scale[d] = sc;
    shift[d] = bb[d] - mean * sc;
}

// in-place BN on tok (bf16)
__global__ __launch_bounds__(256) void bn_apply_kernel(
    u16* __restrict__ tok, const float* __restrict__ scale,
    const float* __restrict__ shift)
{
    size_t i = (size_t)blockIdx.x * 256 + threadIdx.x;
    int d = (int)(i & 511);
    tok[i] = f2b(b2f(tok[i]) * scale[d] + shift[d]);
}

// out[(b*T+t)*C+c] = b_head[t]*stdev[r]+means[r]  (split-K partials add onto it)
__global__ __launch_bounds__(256) void head_init_kernel(
    float* __restrict__ out, const float* __restrict__ b_head,
    const float* __restrict__ stdev, const float* __restrict__ means)
{
    int i = blockIdx.x * 256 + threadIdx.x;
    int c = i & 31, t = (i >> 5) & 511, b = i >> 14;
    int r = b * 32 + c;
    out[i] = b_head[t] * stdev[r] + means[r];
}

// ---------------------------------------------------------------------------
// Launch
// ---------------------------------------------------------------------------
extern "C" void kernel_launch(void* const* d_in, const int* in_sizes, int n_in,
                              void* d_out, int out_size, void* d_ws, size_t ws_size,
                              hipStream_t stream)
{
    const float* x_enc  = (const float*)d_in[0];
    const float* W_val  = (const float*)d_in[1];
    const float* Wq     = (const float*)d_in[2];
    const float* bq     = (const float*)d_in[3];
    const float* Wk     = (const float*)d_in[4];
    const float* bk     = (const float*)d_in[5];
    const float* Wv     = (const float*)d_in[6];
    const float* bv     = (const float*)d_in[7];
    const float* Wo     = (const float*)d_in[8];
    const float* bo     = (const float*)d_in[9];
    const float* Wc1    = (const float*)d_in[10];
    const float* bc1    = (const float*)d_in[11];
    const float* Wc2    = (const float*)d_in[12];
    const float* bc2    = (const float*)d_in[13];
    const float* ln1_g  = (const float*)d_in[14];
    const float* ln1_b  = (const float*)d_in[15];
    const float* ln2_g  = (const float*)d_in[16];
    const float* ln2_b  = (const float*)d_in[17];
    const float* bn_g   = (const float*)d_in[18];
    const float* bn_b   = (const float*)d_in[19];
    const float* W_head = (const float*)d_in[20];
    const float* b_head = (const float*)d_in[21];
    float* out = (float*)d_out;

    // --- adaptive chunk size: largest CH with tok + 3 units + weights fitting
    const size_t tailBytes = (2 * kR + 4 * kD) * sizeof(float);
    const size_t headWb = (size_t)512 * 32768;   // W_head bf16 overlay elems
    int CH = 0; size_t unit = 0, region = 0;
    const int cands[4] = {1024, 512, 256, 128};
    for (int ci = 0; ci < 4; ci++) {
        size_t u = (size_t)cands[ci] * 64 * kD;
        size_t reg = 3 * u + kWbElems;
        if (reg < headWb) reg = headWb;
        size_t need = ((size_t)kM * kD + reg) * 2 + tailBytes;
        if (need <= ws_size) { CH = cands[ci]; unit = u; region = reg; break; }
    }
    if (CH == 0) {
        hipLaunchKernelGGL(fill_kernel, dim3((out_size + 255) / 256), dim3(256), 0,
                           stream, out, 1.0e6f, out_size);
        return;
    }
    const int nch = kR / CH;
    const int chRows = CH * 64;

    u16* tokb = (u16*)d_ws;
    u16* s0  = tokb + (size_t)kM * kD;
    u16* s1  = s0 + unit;
    u16* s2  = s1 + unit;
    u16* wbL = s2 + unit;
    u16* wbH = s0;
    u16* wQKV = wbL;                       // [1536][512]
    u16* wO   = wQKV + (size_t)1536 * 512; // [512][512]
    u16* wC1  = wO + (size_t)512 * 512;    // [2048][512]
    u16* wC2  = wC1 + (size_t)2048 * 512;  // [512][2048]
    float* tail = (float*)(s0 + region);
    float* means    = tail;
    float* stdevp   = means + kR;
    float* bn_sums  = stdevp + kR;
    float* bn_sumsq = bn_sums + kD;
    float* bn_scale = bn_sumsq + kD;
    float* bn_shift = bn_scale + kD;

    hipLaunchKernelGGL(instnorm_stats_kernel, dim3(kB), dim3(256), 0, stream,
                       x_enc, means, stdevp);
    hipLaunchKernelGGL(patch_embed_kernel, dim3(kM), dim3(256), 0, stream,
                       x_enc, W_val, means, stdevp, tokb);

    const dim3 blk(256);
    const dim3 tr8(8, 8, 1);
    const int mt = chRows / 128;   // 128-row M tiles per chunk

    for (int i = 0; i < kNL; i++) {
        const float* Wq_i = Wq + (size_t)i * kD * kD;
        const float* Wk_i = Wk + (size_t)i * kD * kD;
        const float* Wv_i = Wv + (size_t)i * kD * kD;
        const float* Wo_i = Wo + (size_t)i * kD * kD;
        const float* Wc1_i = Wc1 + (size_t)i * kD * kDFF;
        const float* Wc2_i = Wc2 + (size_t)i * kDFF * kD;
        const float* bq_i = bq + i * kD, *bk_i = bk + i * kD, *bv_i = bv + i * kD;

        hipLaunchKernelGGL(transpose_cvt_kernel, tr8, blk, 0, stream,
                           Wq_i, wQKV, kD, kD, 0, 0);
        hipLaunchKernelGGL(transpose_cvt_kernel, tr8, blk, 0, stream,
                           Wk_i, wQKV + (size_t)512 * 512, kD, kD, 0, 0);
        hipLaunchKernelGGL(transpose_cvt_kernel, tr8, blk, 0, stream,
                           Wv_i, wQKV + (size_t)1024 * 512, kD, kD, 0, 0);
        hipLaunchKernelGGL(transpose_cvt_kernel, tr8, blk, 0, stream,
                           Wo_i, wO, kD, kD, 0, 0);
        hipLaunchKernelGGL(transpose_cvt_kernel, dim3(8, 32, 1), blk, 0, stream,
                           Wc1_i, wC1, kDFF, kD, 0, 0);
        hipLaunchKernelGGL(transpose_cvt_kernel, dim3(32, 8, 1), blk, 0, stream,
                           Wc2_i, wC2, kD, kDFF, 0, 0);

        for (int ch = 0; ch < nch; ch++) {
            u16* tokc = tokb + (size_t)ch * chRows * kD;
            // fused QKV: N=1536, routed to s0/s1/s2
            hipLaunchKernelGGL((mfma_gemm<0>), dim3(12, mt, 1), blk, 0, stream,
                               tokc, wQKV, bq_i, bk_i, bv_i, s0, s1, s2,
                               nullptr, nullptr, kD, kD, kD, kD);
            hipLaunchKernelGGL(attn_mfma_kernel, dim3(CH), blk, 0, stream,
                               s0, s1, s2);
            // tok += attn_out @ Wo + bo
            hipLaunchKernelGGL((mfma_gemm<1>), dim3(4, mt, 1), blk, 0, stream,
                               s0, wO, bo + i * kD, nullptr, nullptr,
                               tokc, nullptr, nullptr, nullptr, nullptr,
                               kD, kD, kD, kD);
            // y = LN1(tok) -> s0
            hipLaunchKernelGGL(ln_kernel, dim3(chRows / 4), blk, 0, stream,
                               tokc, ln1_g + i * kD, ln1_b + i * kD, s0);
            // FFN in two DFF/2 halves; h lives in s1:s2 (2 units)
            for (int half = 0; half < 2; half++) {
                const u16* wc1h = wC1 + (size_t)half * 1024 * 512;
                const u16* wc2h = wC2 + (size_t)half * 1024;   // k-offset
                const float* bc1h = bc1 + (size_t)i * kDFF + half * 1024;
                hipLaunchKernelGGL((mfma_gemm<2>), dim3(8, mt, 1), blk, 0, stream,
                                   s0, wc1h, bc1h, nullptr, nullptr,
                                   s1, nullptr, nullptr, nullptr, nullptr,
                                   kD, kD, kD, 1024);
                hipLaunchKernelGGL((mfma_gemm<1>), dim3(4, mt, 1), blk, 0, stream,
                                   s1, wc2h, (half == 0) ? (bc2 + i * kD) : nullptr,
                                   nullptr, nullptr, tokc, nullptr, nullptr,
                                   nullptr, nullptr, 1024, 1024, kDFF, kD);
            }
            // tok = LN2(tok) in place
            hipLaunchKernelGGL(ln_kernel, dim3(chRows / 4), blk, 0, stream,
                               tokc, ln2_g + i * kD, ln2_b + i * kD, tokc);
        }
    }

    // BatchNorm (stats -> apply in place on tok)
    hipLaunchKernelGGL(zero_kernel, dim3(1), dim3(1024), 0, stream, bn_sums, 2 * kD);
    hipLaunchKernelGGL(bn_stats_kernel, dim3(kM / 256), dim3(512), 0, stream,
                       tokb, bn_sums, bn_sumsq);
    hipLaunchKernelGGL(bn_final_kernel, dim3(1), dim3(512), 0, stream,
                       bn_sums, bn_sumsq, bn_g, bn_b, bn_scale, bn_shift);
    hipLaunchKernelGGL(bn_apply_kernel, dim3((int)((size_t)kM * kD / 256)), blk, 0,
                       stream, tokb, bn_scale, bn_shift);

    // head weights: wbH[t][n*512+d] = W_head[(d*64+n)*512+t]  (k' = n*512+d)
    hipLaunchKernelGGL(transpose_cvt_kernel, dim3(8, 8, 64), blk, 0, stream,
                       W_head, wbH, 64 * 512, 32768, 512, 512);
    // out = b_head*stdev+mean, then split-K MFMA adds acc*stdev
    hipLaunchKernelGGL(head_init_kernel, dim3(out_size / 256), blk, 0, stream,
                       out, b_head, stdevp, means);
    // A = tok viewed as [1024][32768] (k'=n*512+d is the flat tok order)
    hipLaunchKernelGGL((mfma_gemm<3>), dim3(4, 8, 8), blk, 0, stream,
                       tokb, wbH, nullptr, nullptr, nullptr,
                       nullptr, nullptr, nullptr, out, stdevp,
                       4096, 32768, 32768, kT);
}

// Round 6
// 3237.017 us; speedup vs baseline: 1.0752x; 1.0752x over previous
//
#include <hip/hip_runtime.h>
#include <math.h>

// ---------------------------------------------------------------------------
// Problem constants (PatchTST-style transformer)
// ---------------------------------------------------------------------------
namespace {
constexpr int kB = 32, kT = 512, kC = 32, kD = 512, kDFF = 2048, kNL = 3;
constexpr int kP = 16, kStride = 8, kN = 64;
constexpr int kR = kB * kC;      // 1024 independent (b,c) series
constexpr int kM = kR * kN;      // 65536 tokens total
constexpr size_t kWbElems = (size_t)1536 * 512 + 512 * 512 + 2048 * 512 + 512 * 2048;
}

typedef unsigned short u16;
typedef __attribute__((ext_vector_type(8))) short short8;   // 8 bf16 (4 VGPRs)
typedef __attribute__((ext_vector_type(4))) float f32x4;    // MFMA accumulator

__device__ __forceinline__ float b2f(u16 u) {
    return __uint_as_float(((unsigned int)u) << 16);
}
__device__ __forceinline__ u16 f2b(float f) {
    unsigned int x = __float_as_uint(f);
    return (u16)((x + 0x7fffu + ((x >> 16) & 1u)) >> 16);
}

// async global->LDS, 16B per lane (builtin: IR-visible, __syncthreads-safe).
__device__ __forceinline__ void async_copy16(const u16* g, u16* l) {
    __builtin_amdgcn_global_load_lds(
        (const __attribute__((address_space(1))) unsigned int*)g,
        (__attribute__((address_space(3))) unsigned int*)l, 16, 0, 0);
}

// ---------------------------------------------------------------------------
// Sentinel fill (workspace-too-small diagnostic)
// ---------------------------------------------------------------------------
__global__ void fill_kernel(float* __restrict__ p, float val, int n)
{
    int i = blockIdx.x * blockDim.x + threadIdx.x;
    if (i < n) p[i] = val;
}

// ---------------------------------------------------------------------------
// Instance-norm stats per (b,c)
// ---------------------------------------------------------------------------
__global__ __launch_bounds__(256) void instnorm_stats_kernel(
    const float* __restrict__ x, float* __restrict__ means, float* __restrict__ stdev)
{
    int b = blockIdx.x;
    int c = threadIdx.x & 31;
    int g = threadIdx.x >> 5;
    float s = 0.f, sq = 0.f;
    for (int t = g; t < kT; t += 8) {
        float v = x[(size_t)(b * kT + t) * kC + c];
        s += v; sq += v * v;
    }
    __shared__ float ss[8][32], ssq[8][32];
    ss[g][c] = s; ssq[g][c] = sq;
    __syncthreads();
    if (g == 0) {
        float S = 0.f, SQ = 0.f;
        for (int i = 0; i < 8; i++) { S += ss[i][c]; SQ += ssq[i][c]; }
        float m = S / kT;
        float var = SQ / kT - m * m;
        means[b * kC + c] = m;
        stdev[b * kC + c] = sqrtf(var + 1e-5f);
    }
}

// ---------------------------------------------------------------------------
// Patch embed (bf16 out)
// ---------------------------------------------------------------------------
__global__ __launch_bounds__(256) void patch_embed_kernel(
    const float* __restrict__ x, const float* __restrict__ Wval,
    const float* __restrict__ means, const float* __restrict__ stdev,
    u16* __restrict__ tok)
{
    int m = blockIdx.x;
    int r = m >> 6, n = m & 63;
    int b = r >> 5, c = r & 31;
    __shared__ float patch[kP];
    if (threadIdx.x < kP) {
        int t = n * kStride + threadIdx.x;
        if (t > kT - 1) t = kT - 1;
        patch[threadIdx.x] = (x[(size_t)(b * kT + t) * kC + c] - means[r]) / stdev[r];
    }
    __syncthreads();
    for (int d = threadIdx.x; d < kD; d += 256) {
        float acc = 0.f;
        #pragma unroll
        for (int p = 0; p < kP; p++) acc += patch[p] * Wval[p * kD + d];
        int j = d >> 1;
        float freq = expf(-(float)(2 * j) * (9.210340371976184f / (float)kD));
        float ang = (float)n * freq;
        float pe = (d & 1) ? cosf(ang) : sinf(ang);
        tok[(size_t)m * kD + d] = f2b(acc + pe);
    }
}

// ---------------------------------------------------------------------------
// Transpose + fp32->bf16 convert: out[n*ldo + k] = f2b(in[k*ldi + n])
// per z-slice: in += z*zin, out += z*zout.  grid (K/64, N/64, Z), 256 thr.
// ---------------------------------------------------------------------------
__global__ __launch_bounds__(256) void transpose_cvt_kernel(
    const float* __restrict__ in, u16* __restrict__ outp,
    int ldi, int ldo, int zin, int zout)
{
    __shared__ float tile[64][65];
    const float* ib = in + (size_t)blockIdx.z * zin;
    u16* ob = outp + (size_t)blockIdx.z * zout;
    int k0 = blockIdx.x * 64, n0 = blockIdx.y * 64;
    int tn = threadIdx.x & 63, tk0 = threadIdx.x >> 6;
    #pragma unroll
    for (int kk = tk0; kk < 64; kk += 4)
        tile[kk][tn] = ib[(size_t)(k0 + kk) * ldi + n0 + tn];
    __syncthreads();
    int wk = threadIdx.x & 63, wn0 = threadIdx.x >> 6;
    #pragma unroll
    for (int nn = wn0; nn < 64; nn += 4)
        ob[(size_t)(n0 + nn) * ldo + k0 + wk] = f2b(tile[wk][nn]);
}

// ---------------------------------------------------------------------------
// MFMA bf16 GEMM core, 128x128 tile, BK=64, 256 thr (4 waves 2x2), m97
// structure (2x __syncthreads per K-step; compiler-managed waits; multi-
// block-per-CU overlap hides the barrier drain — m114).  R5-verified:
// 0 bank conflicts, head-class 147->128 us vs R0.
//
// LDS 32 KiB: As/Bs [128 rows][64 cols], chunk-XOR swizzle: 16B phys chunk
// p of row r holds logical chunk p^(r&7).  Staging pre-swizzles the GLOBAL
// source chunk per lane (DMA dest linear).
//
// A: [M][lda] bf16 row-major.  B: [N][ldb] bf16 N-MAJOR (row n = output col).
// grid: (N/128, M/128, Z) — Z>1 = split-K (global k = z*K + kb), EPI 3 only.
// EPI 0: qkv — dst/bias by 512-col group: C0/C1/C2, bias/auxb1/auxb2
// EPI 1: C0[r*ldc+c] += acc + (bias?bias[c]:0)       (bf16 rmw)
// EPI 2: C0[r*ldc+c]  = gelu_erf(acc + bias[c])
// EPI 3: fout[z*1024*512 + r*ldc + c] = acc          (fp32 split-K partials)
// Wrapper kernels below give each class a distinct rocprof name.
// ---------------------------------------------------------------------------
template<int EPI>
__device__ __forceinline__ void gemm_body(
    const u16* __restrict__ A, const u16* __restrict__ B,
    const float* __restrict__ bias, const float* __restrict__ auxb1,
    const float* __restrict__ auxb2,
    u16* __restrict__ C0, u16* __restrict__ C1, u16* __restrict__ C2,
    float* __restrict__ fout,
    int K, int lda, int ldb, int ldc)
{
    __shared__ alignas(16) u16 As[128 * 64];   // 16 KiB
    __shared__ alignas(16) u16 Bs[128 * 64];   // 16 KiB

    const int tid  = threadIdx.x;
    const int lane = tid & 63;
    const int wave = tid >> 6;
    const int wm   = wave >> 1;        // 0..1
    const int wn   = wave & 1;         // 0..1

    // bijective XCD swizzle (m204) over the (x,y) grid plane
    const int nwg  = gridDim.x * gridDim.y;
    const int orig = blockIdx.y * gridDim.x + blockIdx.x;
    const int qq = nwg >> 3, rr = nwg & 7;
    const int xcd = orig & 7, loc = orig >> 3;
    const int wg  = (xcd < rr) ? (xcd * (qq + 1) + loc)
                               : (rr * (qq + 1) + (xcd - rr) * qq + loc);
    const int row0 = (wg / gridDim.x) * 128;
    const int col0 = (wg % gridDim.x) * 128;
    const size_t zoff = (size_t)blockIdx.z * K;

    // staging: 8 lanes/row (8x16B = 128B row), 32 rows per async round,
    // 4 rounds per matrix.  Lane fetches logical chunk (tid&7)^(srow&7) so
    // the linear DMA dest (base + tid*16B) yields phys chunk p = q^(r&7).
    const int srow = tid >> 3;                         // 0..31
    const int scol = (((tid & 7) ^ (srow & 7)) << 3);
    const u16* const Ag = A + (size_t)(row0 + srow) * lda + zoff + scol;
    const u16* const Bg = B + (size_t)(col0 + srow) * ldb + zoff + scol;
    u16* const AsW = As + (wave << 9);   // this wave's 8-row piece per round
    u16* const BsW = Bs + (wave << 9);

    // fragment reads: logical chunk q (=lane>>4 for k-half 0; ^4 for half 1)
    // of row r sits at phys q^(r&7); r&7 == lane&7 within each 16-row group.
    const int fr = lane & 15;
    const int pc = (lane >> 4) ^ (lane & 7);
    const int a0 = ((wm << 6) + fr) * 64 + (pc << 3);
    const int a1 = ((wm << 6) + fr) * 64 + ((pc ^ 4) << 3);
    const int b0 = ((wn << 6) + fr) * 64 + (pc << 3);
    const int b1 = ((wn << 6) + fr) * 64 + ((pc ^ 4) << 3);

    short8 af[4], bfr[4];
    f32x4 acc[4][4];
    #pragma unroll
    for (int i = 0; i < 4; i++)
        #pragma unroll
        for (int j = 0; j < 4; j++)
            acc[i][j] = (f32x4){0.f, 0.f, 0.f, 0.f};

    for (int kb = 0; kb < K; kb += 64) {
        __syncthreads();
        #pragma unroll
        for (int c = 0; c < 4; c++) {
            async_copy16(Ag + kb + (size_t)(c * 32) * lda, AsW + c * 2048);
            async_copy16(Bg + kb + (size_t)(c * 32) * ldb, BsW + c * 2048);
        }
        __syncthreads();
        // k-half 0
        #pragma unroll
        for (int mi = 0; mi < 4; mi++) af[mi]  = *(const short8*)&As[a0 + (mi << 10)];
        #pragma unroll
        for (int ni = 0; ni < 4; ni++) bfr[ni] = *(const short8*)&Bs[b0 + (ni << 10)];
        #pragma unroll
        for (int mi = 0; mi < 4; mi++)
            #pragma unroll
            for (int ni = 0; ni < 4; ni++)
                acc[mi][ni] = __builtin_amdgcn_mfma_f32_16x16x32_bf16(
                    af[mi], bfr[ni], acc[mi][ni], 0, 0, 0);
        // k-half 1
        #pragma unroll
        for (int mi = 0; mi < 4; mi++) af[mi]  = *(const short8*)&As[a1 + (mi << 10)];
        #pragma unroll
        for (int ni = 0; ni < 4; ni++) bfr[ni] = *(const short8*)&Bs[b1 + (ni << 10)];
        #pragma unroll
        for (int mi = 0; mi < 4; mi++)
            #pragma unroll
            for (int ni = 0; ni < 4; ni++)
                acc[mi][ni] = __builtin_amdgcn_mfma_f32_16x16x32_bf16(
                    af[mi], bfr[ni], acc[mi][ni], 0, 0, 0);
    }

    // epilogue: C/D layout col=lane&15, row=(lane>>4)*4+i  [m89-verified]
    const int er = (lane >> 4) << 2;
    const int ec = lane & 15;
    u16* dsel = C0;
    const float* bsel = bias;
    if (EPI == 0) {
        int sub = col0 >> 9;
        dsel = (sub == 0) ? C0 : ((sub == 1) ? C1 : C2);
        bsel = (sub == 0) ? bias : ((sub == 1) ? auxb1 : auxb2);
    }
    #pragma unroll
    for (int mi = 0; mi < 4; mi++) {
        #pragma unroll
        for (int ni = 0; ni < 4; ni++) {
            #pragma unroll
            for (int i = 0; i < 4; i++) {
                int r  = row0 + (wm << 6) + (mi << 4) + er + i;
                int cc = col0 + (wn << 6) + (ni << 4) + ec;
                float v = acc[mi][ni][i];
                if (EPI == 0) {
                    int cl = cc & 511;
                    dsel[(size_t)r * 512 + cl] = f2b(v + bsel[cl]);
                } else if (EPI == 1) {
                    size_t o = (size_t)r * ldc + cc;
                    float bb2 = bias ? bias[cc] : 0.f;
                    C0[o] = f2b(b2f(C0[o]) + v + bb2);
                } else if (EPI == 2) {
                    size_t o = (size_t)r * ldc + cc;
                    float z = v + bias[cc];
                    C0[o] = f2b(0.5f * z * (1.f + erff(z * 0.7071067811865475f)));
                } else {
                    // disjoint fp32 partials per z-slice (no atomics)
                    fout[((size_t)blockIdx.z << 19) + (size_t)r * ldc + cc] = v;
                }
            }
        }
    }
}

#define GEMM_ARGS \
    const u16* __restrict__ A, const u16* __restrict__ B, \
    const float* __restrict__ bias, const float* __restrict__ auxb1, \
    const float* __restrict__ auxb2, \
    u16* __restrict__ C0, u16* __restrict__ C1, u16* __restrict__ C2, \
    float* __restrict__ fout, \
    int K, int lda, int ldb, int ldc
#define GEMM_PASS A, B, bias, auxb1, auxb2, C0, C1, C2, fout, K, lda, ldb, ldc

__global__ __launch_bounds__(256) void gemm_qkv(GEMM_ARGS)   { gemm_body<0>(GEMM_PASS); }
__global__ __launch_bounds__(256) void gemm_resid(GEMM_ARGS) { gemm_body<1>(GEMM_PASS); }
__global__ __launch_bounds__(256) void gemm_gelu(GEMM_ARGS)  { gemm_body<2>(GEMM_PASS); }
__global__ __launch_bounds__(256) void gemm_head(GEMM_ARGS)  { gemm_body<3>(GEMM_PASS); }

// ---------------------------------------------------------------------------
// Batched in-place 64x64 transpose of V head-tiles:
//   v[series*64 + n][h*64 + e]  ->  v[series*64 + e][h*64 + n]
// so attention's PV B-operand becomes a vectorized b128 row load (removes
// the 64-scalar-u16-per-lane global gather).  One wave per tile; LDS pad 72
// keeps b128 writes 16B-aligned (144B row stride).  grid CH*2 x 256 thr.
// ---------------------------------------------------------------------------
__global__ __launch_bounds__(256) void vtr_kernel(u16* __restrict__ v)
{
    __shared__ u16 tl[4][64 * 72];
    const int tid = threadIdx.x;
    const int wave = tid >> 6, lane = tid & 63;
    const int sr = lane >> 3, ch = lane & 7;
    const int tile = blockIdx.x * 4 + wave;
    const int series = tile >> 3, h = tile & 7;
    u16* g = v + (size_t)series * 64 * kD + h * 64;
    u16* T = tl[wave];
    short8 rd[8];
    #pragma unroll
    for (int r = 0; r < 8; r++)
        rd[r] = *(const short8*)(g + (size_t)(r * 8 + sr) * kD + ch * 8);
    #pragma unroll
    for (int r = 0; r < 8; r++)
        *(short8*)&T[(r * 8 + sr) * 72 + ch * 8] = rd[r];
    __syncthreads();
    #pragma unroll
    for (int r = 0; r < 8; r++) {
        short8 wr;
        #pragma unroll
        for (int q = 0; q < 8; q++)
            wr[q] = (short)T[(ch * 8 + q) * 72 + (r * 8 + sr)];
        *(short8*)(g + (size_t)(r * 8 + sr) * kD + ch * 8) = wr;
    }
}

// ---------------------------------------------------------------------------
// MFMA attention. One block per series; 4 waves; wave w does heads 2w, 2w+1.
// q,k: bf16 [rows=64*series][512]; v PRE-TRANSPOSED per head-tile (vtr).
// Output in place over q.
// ---------------------------------------------------------------------------
__global__ __launch_bounds__(256) void attn_mfma_kernel(
    u16* __restrict__ qbuf, const u16* __restrict__ kbuf,
    const u16* __restrict__ vbuf)
{
    __shared__ u16 P[4][64 * 64];   // 8 KB per wave
    const int tid = threadIdx.x;
    const int wave = tid >> 6, lane = tid & 63;
    const int quad = lane >> 4, l15 = lane & 15;
    const size_t base = (size_t)blockIdx.x * 64 * kD;
    u16* Pw = P[wave];

    for (int hh = 0; hh < 2; hh++) {
        const int h = wave * 2 + hh;
        const u16* qh = qbuf + base + h * 64;
        const u16* kh = kbuf + base + h * 64;
        const u16* vh = vbuf + base + h * 64;

        short8 af[4][2], bf[4][2];
        #pragma unroll
        for (int mi = 0; mi < 4; mi++)
            #pragma unroll
            for (int kt = 0; kt < 2; kt++)
                af[mi][kt] = *(const short8*)(qh + (size_t)(mi * 16 + l15) * kD
                                              + kt * 32 + quad * 8);
        #pragma unroll
        for (int ni = 0; ni < 4; ni++)
            #pragma unroll
            for (int kt = 0; kt < 2; kt++)
                bf[ni][kt] = *(const short8*)(kh + (size_t)(ni * 16 + l15) * kD
                                              + kt * 32 + quad * 8);
        f32x4 S[4][4];
        #pragma unroll
        for (int mi = 0; mi < 4; mi++)
            #pragma unroll
            for (int ni = 0; ni < 4; ni++)
                S[mi][ni] = (f32x4){0.f, 0.f, 0.f, 0.f};
        #pragma unroll
        for (int mi = 0; mi < 4; mi++)
            #pragma unroll
            for (int ni = 0; ni < 4; ni++) {
                S[mi][ni] = __builtin_amdgcn_mfma_f32_16x16x32_bf16(
                    af[mi][0], bf[ni][0], S[mi][ni], 0, 0, 0);
                S[mi][ni] = __builtin_amdgcn_mfma_f32_16x16x32_bf16(
                    af[mi][1], bf[ni][1], S[mi][ni], 0, 0, 0);
            }

        #pragma unroll
        for (int mi = 0; mi < 4; mi++) {
            #pragma unroll
            for (int i = 0; i < 4; i++) {
                float mx = -1e30f;
                #pragma unroll
                for (int ni = 0; ni < 4; ni++) {
                    float v = S[mi][ni][i] * 0.125f;
                    S[mi][ni][i] = v;
                    mx = fmaxf(mx, v);
                }
                #pragma unroll
                for (int off = 1; off < 16; off <<= 1)
                    mx = fmaxf(mx, __shfl_xor(mx, off));
                float sum = 0.f;
                #pragma unroll
                for (int ni = 0; ni < 4; ni++) {
                    float e = expf(S[mi][ni][i] - mx);
                    S[mi][ni][i] = e;
                    sum += e;
                }
                #pragma unroll
                for (int off = 1; off < 16; off <<= 1)
                    sum += __shfl_xor(sum, off);
                float inv = 1.f / sum;
                #pragma unroll
                for (int ni = 0; ni < 4; ni++)
                    Pw[(mi * 16 + quad * 4 + i) * 64 + ni * 16 + l15] =
                        f2b(S[mi][ni][i] * inv);
            }
        }
        __syncthreads();

        // v is tile-transposed: vh[(e)*kD + n] = V[n][e] -> vector loads,
        // identical pattern to the K loads.
        short8 bv[4][2];
        #pragma unroll
        for (int ni = 0; ni < 4; ni++)
            #pragma unroll
            for (int kt = 0; kt < 2; kt++)
                bv[ni][kt] = *(const short8*)(vh + (size_t)(ni * 16 + l15) * kD
                                              + kt * 32 + quad * 8);
        short8 pa[4][2];
        #pragma unroll
        for (int mi = 0; mi < 4; mi++)
            #pragma unroll
            for (int kt = 0; kt < 2; kt++)
                pa[mi][kt] = *(const short8*)&Pw[(mi * 16 + l15) * 64
                                                 + kt * 32 + quad * 8];
        f32x4 O[4][4];
        #pragma unroll
        for (int mi = 0; mi < 4; mi++)
            #pragma unroll
            for (int ni = 0; ni < 4; ni++)
                O[mi][ni] = (f32x4){0.f, 0.f, 0.f, 0.f};
        #pragma unroll
        for (int mi = 0; mi < 4; mi++)
            #pragma unroll
            for (int ni = 0; ni < 4; ni++) {
                O[mi][ni] = __builtin_amdgcn_mfma_f32_16x16x32_bf16(
                    pa[mi][0], bv[ni][0], O[mi][ni], 0, 0, 0);
                O[mi][ni] = __builtin_amdgcn_mfma_f32_16x16x32_bf16(
                    pa[mi][1], bv[ni][1], O[mi][ni], 0, 0, 0);
            }
        u16* qo = qbuf + base + h * 64;
        #pragma unroll
        for (int mi = 0; mi < 4; mi++)
            #pragma unroll
            for (int ni = 0; ni < 4; ni++)
                #pragma unroll
                for (int i = 0; i < 4; i++)
                    qo[(size_t)(mi * 16 + quad * 4 + i) * kD + ni * 16 + l15] =
                        f2b(O[mi][ni][i]);
        __syncthreads();
    }
}

// ---------------------------------------------------------------------------
// Row LayerNorm over D=512, bf16 in/out, in-place safe. 4 rows per block.
// ---------------------------------------------------------------------------
__global__ __launch_bounds__(256) void ln_kernel(
    const u16* __restrict__ x, const float* __restrict__ g,
    const float* __restrict__ bb, u16* __restrict__ y)
{
    size_t row = (size_t)blockIdx.x * 4 + (threadIdx.x >> 6);
    int lane = threadIdx.x & 63;
    float v[8];
    float s = 0.f;
    #pragma unroll
    for (int i = 0; i < 8; i++) {
        v[i] = b2f(x[row * kD + lane + i * 64]);
        s += v[i];
    }
    #pragma unroll
    for (int off = 32; off; off >>= 1) s += __shfl_xor(s, off);
    float mean = s * (1.f / kD);
    float sq = 0.f;
    #pragma unroll
    for (int i = 0; i < 8; i++) { float d = v[i] - mean; sq += d * d; }
    #pragma unroll
    for (int off = 32; off; off >>= 1) sq += __shfl_xor(sq, off);
    float inv = 1.f / sqrtf(sq * (1.f / kD) + 1e-5f);
    #pragma unroll
    for (int i = 0; i < 8; i++) {
        int d = lane + i * 64;
        y[row * kD + d] = f2b((v[i] - mean) * inv * g[d] + bb[d]);
    }
}

// ---------------------------------------------------------------------------
// BatchNorm pieces
// ---------------------------------------------------------------------------
__global__ void zero_kernel(float* __restrict__ p, int n)
{
    int i = blockIdx.x * blockDim.x + threadIdx.x;
    if (i < n) p[i] = 0.f;
}

__global__ __launch_bounds__(512) void bn_stats_kernel(
    const u16* __restrict__ tok, float* __restrict__ sums, float* __restrict__ sumsq)
{
    int d = threadIdx.x;
    float s = 0.f, sq = 0.f;
    int row0 = blockIdx.x * 256;
    for (int row = row0; row < row0 + 256; row++) {
        float v = b2f(tok[(size_t)row * kD + d]);
        s += v; sq += v * v;
    }
    atomicAdd(&sums[d], s);
    atomicAdd(&sumsq[d], sq);
}

__global__ __launch_bounds__(512) void bn_final_kernel(
    const float* __restrict__ sums, const float* __restrict__ sumsq,
    const float* __restrict__ g, const float* __restrict__ bb,
    float* __restrict__ scale, float* __restrict__ shift)
{
    int d = threadIdx.x;
    float mean = sums[d] / (float)kM;
    float var = sumsq[d] / (float)kM - mean * mean;
    float sc = g[d] / sqrtf(var + 1e-5f);
    scale[d] = sc;
    shift[d] = bb[d] - mean * sc;
}

// in-place BN on tok (bf16)
__global__ __launch_bounds__(256) void bn_apply_kernel(
    u16* __restrict__ tok, const float* __restrict__ scale,
    const float* __restrict__ shift)
{
    size_t i = (size_t)blockIdx.x * 256 + threadIdx.x;
    int d = (int)(i & 511);
    tok[i] = f2b(b2f(tok[i]) * scale[d] + shift[d]);
}

// reduce split-K head partials (z=16) + bias + instance-denorm:
// out[(b*T+t)*C+c] = (sum_z part[z][r][t] + b_head[t]) * stdev[r] + means[r]
__global__ __launch_bounds__(256) void head_reduce_kernel(
    const float* __restrict__ part, const float* __restrict__ b_head,
    const float* __restrict__ stdev, const float* __restrict__ means,
    float* __restrict__ out)
{
    int j = blockIdx.x * 256 + threadIdx.x;      // [0, 1024*512)
    int r = j >> 9, t = j & 511;
    float s = 0.f;
    #pragma unroll
    for (int z = 0; z < 16; z++) s += part[((size_t)z << 19) + j];
    int b = r >> 5, c = r & 31;
    out[(((size_t)b * kT + t) << 5) + c] = (s + b_head[t]) * stdev[r] + means[r];
}

// ---------------------------------------------------------------------------
// Launch
// ---------------------------------------------------------------------------
extern "C" void kernel_launch(void* const* d_in, const int* in_sizes, int n_in,
                              void* d_out, int out_size, void* d_ws, size_t ws_size,
                              hipStream_t stream)
{
    const float* x_enc  = (const float*)d_in[0];
    const float* W_val  = (const float*)d_in[1];
    const float* Wq     = (const float*)d_in[2];
    const float* bq     = (const float*)d_in[3];
    const float* Wk     = (const float*)d_in[4];
    const float* bk     = (const float*)d_in[5];
    const float* Wv     = (const float*)d_in[6];
    const float* bv     = (const float*)d_in[7];
    const float* Wo     = (const float*)d_in[8];
    const float* bo     = (const float*)d_in[9];
    const float* Wc1    = (const float*)d_in[10];
    const float* bc1    = (const float*)d_in[11];
    const float* Wc2    = (const float*)d_in[12];
    const float* bc2    = (const float*)d_in[13];
    const float* ln1_g  = (const float*)d_in[14];
    const float* ln1_b  = (const float*)d_in[15];
    const float* ln2_g  = (const float*)d_in[16];
    const float* ln2_b  = (const float*)d_in[17];
    const float* bn_g   = (const float*)d_in[18];
    const float* bn_b   = (const float*)d_in[19];
    const float* W_head = (const float*)d_in[20];
    const float* b_head = (const float*)d_in[21];
    float* out = (float*)d_out;

    // --- adaptive chunk size: largest CH with tok + 3 units + weights fitting
    const size_t tailBytes = (2 * kR + 4 * kD) * sizeof(float);
    const size_t headWb = (size_t)512 * 32768;   // W_head bf16 overlay elems
    int CH = 0; size_t unit = 0, region = 0;
    const int cands[4] = {1024, 512, 256, 128};
    for (int ci = 0; ci < 4; ci++) {
        size_t u = (size_t)cands[ci] * 64 * kD;
        size_t reg = 3 * u + kWbElems;
        if (reg < headWb) reg = headWb;
        size_t need = ((size_t)kM * kD + reg) * 2 + tailBytes;
        if (need <= ws_size) { CH = cands[ci]; unit = u; region = reg; break; }
    }
    if (CH == 0) {
        hipLaunchKernelGGL(fill_kernel, dim3((out_size + 255) / 256), dim3(256), 0,
                           stream, out, 1.0e6f, out_size);
        return;
    }
    const int nch = kR / CH;
    const int chRows = CH * 64;

    u16* tokb = (u16*)d_ws;
    u16* s0  = tokb + (size_t)kM * kD;
    u16* s1  = s0 + unit;
    u16* s2  = s1 + unit;
    u16* wbL = s2 + unit;
    u16* wbH = s0;
    u16* wQKV = wbL;                       // [1536][512]
    u16* wO   = wQKV + (size_t)1536 * 512; // [512][512]
    u16* wC1  = wO + (size_t)512 * 512;    // [2048][512]
    u16* wC2  = wC1 + (size_t)2048 * 512;  // [512][2048]
    float* tail = (float*)(s0 + region);
    float* means    = tail;
    float* stdevp   = means + kR;
    float* bn_sums  = stdevp + kR;
    float* bn_sumsq = bn_sums + kD;
    float* bn_scale = bn_sumsq + kD;
    float* bn_shift = bn_scale + kD;

    hipLaunchKernelGGL(instnorm_stats_kernel, dim3(kB), dim3(256), 0, stream,
                       x_enc, means, stdevp);
    hipLaunchKernelGGL(patch_embed_kernel, dim3(kM), dim3(256), 0, stream,
                       x_enc, W_val, means, stdevp, tokb);

    const dim3 blk(256);
    const dim3 tr8(8, 8, 1);
    const int mt = chRows / 128;   // 128-row M tiles per chunk

    for (int i = 0; i < kNL; i++) {
        const float* Wq_i = Wq + (size_t)i * kD * kD;
        const float* Wk_i = Wk + (size_t)i * kD * kD;
        const float* Wv_i = Wv + (size_t)i * kD * kD;
        const float* Wo_i = Wo + (size_t)i * kD * kD;
        const float* Wc1_i = Wc1 + (size_t)i * kD * kDFF;
        const float* Wc2_i = Wc2 + (size_t)i * kDFF * kD;
        const float* bq_i = bq + i * kD, *bk_i = bk + i * kD, *bv_i = bv + i * kD;

        hipLaunchKernelGGL(transpose_cvt_kernel, tr8, blk, 0, stream,
                           Wq_i, wQKV, kD, kD, 0, 0);
        hipLaunchKernelGGL(transpose_cvt_kernel, tr8, blk, 0, stream,
                           Wk_i, wQKV + (size_t)512 * 512, kD, kD, 0, 0);
        hipLaunchKernelGGL(transpose_cvt_kernel, tr8, blk, 0, stream,
                           Wv_i, wQKV + (size_t)1024 * 512, kD, kD, 0, 0);
        hipLaunchKernelGGL(transpose_cvt_kernel, tr8, blk, 0, stream,
                           Wo_i, wO, kD, kD, 0, 0);
        hipLaunchKernelGGL(transpose_cvt_kernel, dim3(8, 32, 1), blk, 0, stream,
                           Wc1_i, wC1, kDFF, kD, 0, 0);
        hipLaunchKernelGGL(transpose_cvt_kernel, dim3(32, 8, 1), blk, 0, stream,
                           Wc2_i, wC2, kD, kDFF, 0, 0);

        for (int ch = 0; ch < nch; ch++) {
            u16* tokc = tokb + (size_t)ch * chRows * kD;
            // fused QKV: N=1536, routed to s0/s1/s2
            hipLaunchKernelGGL(gemm_qkv, dim3(12, mt, 1), blk, 0, stream,
                               tokc, wQKV, bq_i, bk_i, bv_i, s0, s1, s2,
                               nullptr, kD, kD, kD, kD);
            // transpose V head-tiles in place -> vectorized PV loads
            hipLaunchKernelGGL(vtr_kernel, dim3(CH * 2), blk, 0, stream, s2);
            hipLaunchKernelGGL(attn_mfma_kernel, dim3(CH), blk, 0, stream,
                               s0, s1, s2);
            // tok += attn_out @ Wo + bo
            hipLaunchKernelGGL(gemm_resid, dim3(4, mt, 1), blk, 0, stream,
                               s0, wO, bo + i * kD, nullptr, nullptr,
                               tokc, nullptr, nullptr, nullptr,
                               kD, kD, kD, kD);
            // y = LN1(tok) -> s0
            hipLaunchKernelGGL(ln_kernel, dim3(chRows / 4), blk, 0, stream,
                               tokc, ln1_g + i * kD, ln1_b + i * kD, s0);
            // FFN in two DFF/2 halves; h lives in s1 (per half)
            for (int half = 0; half < 2; half++) {
                const u16* wc1h = wC1 + (size_t)half * 1024 * 512;
                const u16* wc2h = wC2 + (size_t)half * 1024;   // k-offset
                const float* bc1h = bc1 + (size_t)i * kDFF + half * 1024;
                hipLaunchKernelGGL(gemm_gelu, dim3(8, mt, 1), blk, 0, stream,
                                   s0, wc1h, bc1h, nullptr, nullptr,
                                   s1, nullptr, nullptr, nullptr,
                                   kD, kD, kD, 1024);
                hipLaunchKernelGGL(gemm_resid, dim3(4, mt, 1), blk, 0, stream,
                                   s1, wc2h, (half == 0) ? (bc2 + i * kD) : nullptr,
                                   nullptr, nullptr, tokc, nullptr, nullptr,
                                   nullptr, 1024, 1024, kDFF, kD);
            }
            // tok = LN2(tok) in place
            hipLaunchKernelGGL(ln_kernel, dim3(chRows / 4), blk, 0, stream,
                               tokc, ln2_g + i * kD, ln2_b + i * kD, tokc);
        }
    }

    // BatchNorm (stats -> apply in place on tok)
    hipLaunchKernelGGL(zero_kernel, dim3(1), dim3(1024), 0, stream, bn_sums, 2 * kD);
    hipLaunchKernelGGL(bn_stats_kernel, dim3(kM / 256), dim3(512), 0, stream,
                       tokb, bn_sums, bn_sumsq);
    hipLaunchKernelGGL(bn_final_kernel, dim3(1), dim3(512), 0, stream,
                       bn_sums, bn_sumsq, bn_g, bn_b, bn_scale, bn_shift);
    hipLaunchKernelGGL(bn_apply_kernel, dim3((int)((size_t)kM * kD / 256)), blk, 0,
                       stream, tokb, bn_scale, bn_shift);

    // head weights: wbH[t][n*512+d] = W_head[(d*64+n)*512+t]  (k' = n*512+d)
    hipLaunchKernelGGL(transpose_cvt_kernel, dim3(8, 8, 64), blk, 0, stream,
                       W_head, wbH, 64 * 512, 32768, 512, 512);
    // split-K z=16 (2 blocks/CU): disjoint fp32 partials into s1, then reduce
    hipLaunchKernelGGL(gemm_head, dim3(4, 8, 16), blk, 0, stream,
                       tokb, wbH, nullptr, nullptr, nullptr,
                       nullptr, nullptr, nullptr, (float*)s1,
                       2048, 32768, 32768, kT);
    hipLaunchKernelGGL(head_reduce_kernel, dim3(kR * kT / 256), blk, 0, stream,
                       (const float*)s1, b_head, stdevp, means, out);
}

// Round 7
// 3213.769 us; speedup vs baseline: 1.0830x; 1.0072x over previous
//
#include <hip/hip_runtime.h>
#include <math.h>

// ---------------------------------------------------------------------------
// Problem constants (PatchTST-style transformer)
// ---------------------------------------------------------------------------
namespace {
constexpr int kB = 32, kT = 512, kC = 32, kD = 512, kDFF = 2048, kNL = 3;
constexpr int kP = 16, kStride = 8, kN = 64;
constexpr int kR = kB * kC;      // 1024 independent (b,c) series
constexpr int kM = kR * kN;      // 65536 tokens total
constexpr size_t kWbElems = (size_t)1536 * 512 + 512 * 512 + 2048 * 512 + 512 * 2048;
}

typedef unsigned short u16;
typedef __attribute__((ext_vector_type(8))) short short8;   // 8 bf16 (4 VGPRs)
typedef __attribute__((ext_vector_type(4))) float f32x4;    // MFMA accumulator

__device__ __forceinline__ float b2f(u16 u) {
    return __uint_as_float(((unsigned int)u) << 16);
}
__device__ __forceinline__ u16 f2b(float f) {
    unsigned int x = __float_as_uint(f);
    return (u16)((x + 0x7fffu + ((x >> 16) & 1u)) >> 16);
}

// async global->LDS, 16B per lane (builtin: IR-visible, __syncthreads-safe).
__device__ __forceinline__ void async_copy16(const u16* g, u16* l) {
    __builtin_amdgcn_global_load_lds(
        (const __attribute__((address_space(1))) unsigned int*)g,
        (__attribute__((address_space(3))) unsigned int*)l, 16, 0, 0);
}

// ---------------------------------------------------------------------------
// Sentinel fill (workspace-too-small diagnostic)
// ---------------------------------------------------------------------------
__global__ void fill_kernel(float* __restrict__ p, float val, int n)
{
    int i = blockIdx.x * blockDim.x + threadIdx.x;
    if (i < n) p[i] = val;
}

// ---------------------------------------------------------------------------
// Instance-norm stats per (b,c)
// ---------------------------------------------------------------------------
__global__ __launch_bounds__(256) void instnorm_stats_kernel(
    const float* __restrict__ x, float* __restrict__ means, float* __restrict__ stdev)
{
    int b = blockIdx.x;
    int c = threadIdx.x & 31;
    int g = threadIdx.x >> 5;
    float s = 0.f, sq = 0.f;
    for (int t = g; t < kT; t += 8) {
        float v = x[(size_t)(b * kT + t) * kC + c];
        s += v; sq += v * v;
    }
    __shared__ float ss[8][32], ssq[8][32];
    ss[g][c] = s; ssq[g][c] = sq;
    __syncthreads();
    if (g == 0) {
        float S = 0.f, SQ = 0.f;
        for (int i = 0; i < 8; i++) { S += ss[i][c]; SQ += ssq[i][c]; }
        float m = S / kT;
        float var = SQ / kT - m * m;
        means[b * kC + c] = m;
        stdev[b * kC + c] = sqrtf(var + 1e-5f);
    }
}

// ---------------------------------------------------------------------------
// Sinusoidal PE table [64][512], computed ONCE (32K transcendentals instead
// of 33.5M in patch_embed — R6: patch_embed was top dispatch, VALUBusy 106%)
// ---------------------------------------------------------------------------
__global__ __launch_bounds__(256) void pe_kernel(float* __restrict__ pe)
{
    int i = blockIdx.x * 256 + threadIdx.x;    // [0, 32768)
    int n = i >> 9, d = i & 511;
    int j = d >> 1;
    float freq = expf(-(float)(2 * j) * (9.210340371976184f / (float)kD));
    float ang = (float)n * freq;
    pe[i] = (d & 1) ? cosf(ang) : sinf(ang);
}

// ---------------------------------------------------------------------------
// Patch embed (bf16 out); PE from precomputed table
// ---------------------------------------------------------------------------
__global__ __launch_bounds__(256) void patch_embed_kernel(
    const float* __restrict__ x, const float* __restrict__ Wval,
    const float* __restrict__ means, const float* __restrict__ stdev,
    const float* __restrict__ pe, u16* __restrict__ tok)
{
    int m = blockIdx.x;
    int r = m >> 6, n = m & 63;
    int b = r >> 5, c = r & 31;
    __shared__ float patch[kP];
    if (threadIdx.x < kP) {
        int t = n * kStride + threadIdx.x;
        if (t > kT - 1) t = kT - 1;
        patch[threadIdx.x] = (x[(size_t)(b * kT + t) * kC + c] - means[r]) / stdev[r];
    }
    __syncthreads();
    const float* pen = pe + (size_t)n * kD;
    for (int d = threadIdx.x; d < kD; d += 256) {
        float acc = 0.f;
        #pragma unroll
        for (int p = 0; p < kP; p++) acc += patch[p] * Wval[p * kD + d];
        tok[(size_t)m * kD + d] = f2b(acc + pen[d]);
    }
}

// ---------------------------------------------------------------------------
// Transpose + fp32->bf16 convert: out[n*ldo + k] = f2b(in[k*ldi + n] * sc[k])
// per z-slice: in += z*zin, out += z*zout.  grid (K/64, N/64, Z), 256 thr.
// scale==nullptr -> 1.0 (scale indexed by the kernel's k dim; for the head
// call k == d, so passing bn_scale folds BatchNorm's scale into W_head).
// ---------------------------------------------------------------------------
__global__ __launch_bounds__(256) void transpose_cvt_kernel(
    const float* __restrict__ in, u16* __restrict__ outp,
    const float* __restrict__ scale,
    int ldi, int ldo, int zin, int zout)
{
    __shared__ float tile[64][65];
    const float* ib = in + (size_t)blockIdx.z * zin;
    u16* ob = outp + (size_t)blockIdx.z * zout;
    int k0 = blockIdx.x * 64, n0 = blockIdx.y * 64;
    int tn = threadIdx.x & 63, tk0 = threadIdx.x >> 6;
    #pragma unroll
    for (int kk = tk0; kk < 64; kk += 4) {
        float sc = scale ? scale[k0 + kk] : 1.f;
        tile[kk][tn] = ib[(size_t)(k0 + kk) * ldi + n0 + tn] * sc;
    }
    __syncthreads();
    int wk = threadIdx.x & 63, wn0 = threadIdx.x >> 6;
    #pragma unroll
    for (int nn = wn0; nn < 64; nn += 4)
        ob[(size_t)(n0 + nn) * ldo + k0 + wk] = f2b(tile[wk][nn]);
}

// Batched 512x512 transposes for Wq/Wk/Wv/Wo (one launch instead of four).
// z=0..2 -> wQKV + z*256K; z=3 -> wO.  grid (8, 8, 4).
__global__ __launch_bounds__(256) void transpose_cvt4_kernel(
    const float* __restrict__ in0, const float* __restrict__ in1,
    const float* __restrict__ in2, const float* __restrict__ in3,
    u16* __restrict__ outQKV, u16* __restrict__ outO)
{
    __shared__ float tile[64][65];
    int z = blockIdx.z;
    const float* ib = (z == 0) ? in0 : (z == 1) ? in1 : (z == 2) ? in2 : in3;
    u16* ob = (z < 3) ? outQKV + (size_t)z * 512 * 512 : outO;
    int k0 = blockIdx.x * 64, n0 = blockIdx.y * 64;
    int tn = threadIdx.x & 63, tk0 = threadIdx.x >> 6;
    #pragma unroll
    for (int kk = tk0; kk < 64; kk += 4)
        tile[kk][tn] = ib[(size_t)(k0 + kk) * 512 + n0 + tn];
    __syncthreads();
    int wk = threadIdx.x & 63, wn0 = threadIdx.x >> 6;
    #pragma unroll
    for (int nn = wn0; nn < 64; nn += 4)
        ob[(size_t)(n0 + nn) * 512 + k0 + wk] = f2b(tile[wk][nn]);
}

// ---------------------------------------------------------------------------
// MFMA bf16 GEMM core, 128x128 tile, BK=64, 256 thr (4 waves 2x2), m97
// structure.  R5-verified: 0 bank conflicts, head-class 147->128 us vs R0.
// LDS 32 KiB; chunk-XOR swizzle p^(r&7); global src pre-swizzled.
// A: [M][lda] bf16 row-major.  B: [N][ldb] bf16 N-MAJOR (row n = output col).
// grid: (N/128, M/128, Z) — Z>1 = split-K (global k = z*K + kb), EPI 3 only.
// EPI 0: qkv   EPI 1: bf16 rmw +bias   EPI 2: gelu   EPI 3: fp32 partials
// ---------------------------------------------------------------------------
template<int EPI>
__device__ __forceinline__ void gemm_body(
    const u16* __restrict__ A, const u16* __restrict__ B,
    const float* __restrict__ bias, const float* __restrict__ auxb1,
    const float* __restrict__ auxb2,
    u16* __restrict__ C0, u16* __restrict__ C1, u16* __restrict__ C2,
    float* __restrict__ fout,
    int K, int lda, int ldb, int ldc)
{
    __shared__ alignas(16) u16 As[128 * 64];   // 16 KiB
    __shared__ alignas(16) u16 Bs[128 * 64];   // 16 KiB

    const int tid  = threadIdx.x;
    const int lane = tid & 63;
    const int wave = tid >> 6;
    const int wm   = wave >> 1;        // 0..1
    const int wn   = wave & 1;         // 0..1

    // bijective XCD swizzle (m204) over the (x,y) grid plane
    const int nwg  = gridDim.x * gridDim.y;
    const int orig = blockIdx.y * gridDim.x + blockIdx.x;
    const int qq = nwg >> 3, rr = nwg & 7;
    const int xcd = orig & 7, loc = orig >> 3;
    const int wg  = (xcd < rr) ? (xcd * (qq + 1) + loc)
                               : (rr * (qq + 1) + (xcd - rr) * qq + loc);
    const int row0 = (wg / gridDim.x) * 128;
    const int col0 = (wg % gridDim.x) * 128;
    const size_t zoff = (size_t)blockIdx.z * K;

    // staging: 8 lanes/row (8x16B = 128B row), 32 rows per async round,
    // 4 rounds per matrix.  Lane fetches logical chunk (tid&7)^(srow&7) so
    // the linear DMA dest (base + tid*16B) yields phys chunk p = q^(r&7).
    const int srow = tid >> 3;                         // 0..31
    const int scol = (((tid & 7) ^ (srow & 7)) << 3);
    const u16* const Ag = A + (size_t)(row0 + srow) * lda + zoff + scol;
    const u16* const Bg = B + (size_t)(col0 + srow) * ldb + zoff + scol;
    u16* const AsW = As + (wave << 9);   // this wave's 8-row piece per round
    u16* const BsW = Bs + (wave << 9);

    // fragment reads: logical chunk q (=lane>>4 for k-half 0; ^4 for half 1)
    // of row r sits at phys q^(r&7); r&7 == lane&7 within each 16-row group.
    const int fr = lane & 15;
    const int pc = (lane >> 4) ^ (lane & 7);
    const int a0 = ((wm << 6) + fr) * 64 + (pc << 3);
    const int a1 = ((wm << 6) + fr) * 64 + ((pc ^ 4) << 3);
    const int b0 = ((wn << 6) + fr) * 64 + (pc << 3);
    const int b1 = ((wn << 6) + fr) * 64 + ((pc ^ 4) << 3);

    short8 af[4], bfr[4];
    f32x4 acc[4][4];
    #pragma unroll
    for (int i = 0; i < 4; i++)
        #pragma unroll
        for (int j = 0; j < 4; j++)
            acc[i][j] = (f32x4){0.f, 0.f, 0.f, 0.f};

    for (int kb = 0; kb < K; kb += 64) {
        __syncthreads();
        #pragma unroll
        for (int c = 0; c < 4; c++) {
            async_copy16(Ag + kb + (size_t)(c * 32) * lda, AsW + c * 2048);
            async_copy16(Bg + kb + (size_t)(c * 32) * ldb, BsW + c * 2048);
        }
        __syncthreads();
        // k-half 0
        #pragma unroll
        for (int mi = 0; mi < 4; mi++) af[mi]  = *(const short8*)&As[a0 + (mi << 10)];
        #pragma unroll
        for (int ni = 0; ni < 4; ni++) bfr[ni] = *(const short8*)&Bs[b0 + (ni << 10)];
        #pragma unroll
        for (int mi = 0; mi < 4; mi++)
            #pragma unroll
            for (int ni = 0; ni < 4; ni++)
                acc[mi][ni] = __builtin_amdgcn_mfma_f32_16x16x32_bf16(
                    af[mi], bfr[ni], acc[mi][ni], 0, 0, 0);
        // k-half 1
        #pragma unroll
        for (int mi = 0; mi < 4; mi++) af[mi]  = *(const short8*)&As[a1 + (mi << 10)];
        #pragma unroll
        for (int ni = 0; ni < 4; ni++) bfr[ni] = *(const short8*)&Bs[b1 + (ni << 10)];
        #pragma unroll
        for (int mi = 0; mi < 4; mi++)
            #pragma unroll
            for (int ni = 0; ni < 4; ni++)
                acc[mi][ni] = __builtin_amdgcn_mfma_f32_16x16x32_bf16(
                    af[mi], bfr[ni], acc[mi][ni], 0, 0, 0);
    }

    // epilogue: C/D layout col=lane&15, row=(lane>>4)*4+i  [m89-verified]
    const int er = (lane >> 4) << 2;
    const int ec = lane & 15;
    u16* dsel = C0;
    const float* bsel = bias;
    if (EPI == 0) {
        int sub = col0 >> 9;
        dsel = (sub == 0) ? C0 : ((sub == 1) ? C1 : C2);
        bsel = (sub == 0) ? bias : ((sub == 1) ? auxb1 : auxb2);
    }
    #pragma unroll
    for (int mi = 0; mi < 4; mi++) {
        #pragma unroll
        for (int ni = 0; ni < 4; ni++) {
            #pragma unroll
            for (int i = 0; i < 4; i++) {
                int r  = row0 + (wm << 6) + (mi << 4) + er + i;
                int cc = col0 + (wn << 6) + (ni << 4) + ec;
                float v = acc[mi][ni][i];
                if (EPI == 0) {
                    int cl = cc & 511;
                    dsel[(size_t)r * 512 + cl] = f2b(v + bsel[cl]);
                } else if (EPI == 1) {
                    size_t o = (size_t)r * ldc + cc;
                    float bb2 = bias ? bias[cc] : 0.f;
                    C0[o] = f2b(b2f(C0[o]) + v + bb2);
                } else if (EPI == 2) {
                    size_t o = (size_t)r * ldc + cc;
                    float z = v + bias[cc];
                    C0[o] = f2b(0.5f * z * (1.f + erff(z * 0.7071067811865475f)));
                } else {
                    // disjoint fp32 partials per z-slice (no atomics)
                    fout[((size_t)blockIdx.z << 19) + (size_t)r * ldc + cc] = v;
                }
            }
        }
    }
}

#define GEMM_ARGS \
    const u16* __restrict__ A, const u16* __restrict__ B, \
    const float* __restrict__ bias, const float* __restrict__ auxb1, \
    const float* __restrict__ auxb2, \
    u16* __restrict__ C0, u16* __restrict__ C1, u16* __restrict__ C2, \
    float* __restrict__ fout, \
    int K, int lda, int ldb, int ldc
#define GEMM_PASS A, B, bias, auxb1, auxb2, C0, C1, C2, fout, K, lda, ldb, ldc

__global__ __launch_bounds__(256) void gemm_qkv(GEMM_ARGS)   { gemm_body<0>(GEMM_PASS); }
__global__ __launch_bounds__(256) void gemm_resid(GEMM_ARGS) { gemm_body<1>(GEMM_PASS); }
__global__ __launch_bounds__(256) void gemm_gelu(GEMM_ARGS)  { gemm_body<2>(GEMM_PASS); }
__global__ __launch_bounds__(256) void gemm_head(GEMM_ARGS)  { gemm_body<3>(GEMM_PASS); }

// ---------------------------------------------------------------------------
// Batched in-place 64x64 transpose of V head-tiles:
//   v[series*64 + n][h*64 + e]  ->  v[series*64 + e][h*64 + n]
// so attention's PV B-operand becomes a vectorized b128 row load.
// ---------------------------------------------------------------------------
__global__ __launch_bounds__(256) void vtr_kernel(u16* __restrict__ v)
{
    __shared__ u16 tl[4][64 * 72];
    const int tid = threadIdx.x;
    const int wave = tid >> 6, lane = tid & 63;
    const int sr = lane >> 3, ch = lane & 7;
    const int tile = blockIdx.x * 4 + wave;
    const int series = tile >> 3, h = tile & 7;
    u16* g = v + (size_t)series * 64 * kD + h * 64;
    u16* T = tl[wave];
    short8 rd[8];
    #pragma unroll
    for (int r = 0; r < 8; r++)
        rd[r] = *(const short8*)(g + (size_t)(r * 8 + sr) * kD + ch * 8);
    #pragma unroll
    for (int r = 0; r < 8; r++)
        *(short8*)&T[(r * 8 + sr) * 72 + ch * 8] = rd[r];
    __syncthreads();
    #pragma unroll
    for (int r = 0; r < 8; r++) {
        short8 wr;
        #pragma unroll
        for (int q = 0; q < 8; q++)
            wr[q] = (short)T[(ch * 8 + q) * 72 + (r * 8 + sr)];
        *(short8*)(g + (size_t)(r * 8 + sr) * kD + ch * 8) = wr;
    }
}

// ---------------------------------------------------------------------------
// MFMA attention. One block per series; 4 waves; wave w does heads 2w, 2w+1.
// q,k: bf16 [rows=64*series][512]; v PRE-TRANSPOSED per head-tile (vtr).
// Output in place over q.
// ---------------------------------------------------------------------------
__global__ __launch_bounds__(256) void attn_mfma_kernel(
    u16* __restrict__ qbuf, const u16* __restrict__ kbuf,
    const u16* __restrict__ vbuf)
{
    __shared__ u16 P[4][64 * 64];   // 8 KB per wave
    const int tid = threadIdx.x;
    const int wave = tid >> 6, lane = tid & 63;
    const int quad = lane >> 4, l15 = lane & 15;
    const size_t base = (size_t)blockIdx.x * 64 * kD;
    u16* Pw = P[wave];

    for (int hh = 0; hh < 2; hh++) {
        const int h = wave * 2 + hh;
        const u16* qh = qbuf + base + h * 64;
        const u16* kh = kbuf + base + h * 64;
        const u16* vh = vbuf + base + h * 64;

        short8 af[4][2], bf[4][2];
        #pragma unroll
        for (int mi = 0; mi < 4; mi++)
            #pragma unroll
            for (int kt = 0; kt < 2; kt++)
                af[mi][kt] = *(const short8*)(qh + (size_t)(mi * 16 + l15) * kD
                                              + kt * 32 + quad * 8);
        #pragma unroll
        for (int ni = 0; ni < 4; ni++)
            #pragma unroll
            for (int kt = 0; kt < 2; kt++)
                bf[ni][kt] = *(const short8*)(kh + (size_t)(ni * 16 + l15) * kD
                                              + kt * 32 + quad * 8);
        f32x4 S[4][4];
        #pragma unroll
        for (int mi = 0; mi < 4; mi++)
            #pragma unroll
            for (int ni = 0; ni < 4; ni++)
                S[mi][ni] = (f32x4){0.f, 0.f, 0.f, 0.f};
        #pragma unroll
        for (int mi = 0; mi < 4; mi++)
            #pragma unroll
            for (int ni = 0; ni < 4; ni++) {
                S[mi][ni] = __builtin_amdgcn_mfma_f32_16x16x32_bf16(
                    af[mi][0], bf[ni][0], S[mi][ni], 0, 0, 0);
                S[mi][ni] = __builtin_amdgcn_mfma_f32_16x16x32_bf16(
                    af[mi][1], bf[ni][1], S[mi][ni], 0, 0, 0);
            }

        #pragma unroll
        for (int mi = 0; mi < 4; mi++) {
            #pragma unroll
            for (int i = 0; i < 4; i++) {
                float mx = -1e30f;
                #pragma unroll
                for (int ni = 0; ni < 4; ni++) {
                    float v = S[mi][ni][i] * 0.125f;
                    S[mi][ni][i] = v;
                    mx = fmaxf(mx, v);
                }
                #pragma unroll
                for (int off = 1; off < 16; off <<= 1)
                    mx = fmaxf(mx, __shfl_xor(mx, off));
                float sum = 0.f;
                #pragma unroll
                for (int ni = 0; ni < 4; ni++) {
                    float e = expf(S[mi][ni][i] - mx);
                    S[mi][ni][i] = e;
                    sum += e;
                }
                #pragma unroll
                for (int off = 1; off < 16; off <<= 1)
                    sum += __shfl_xor(sum, off);
                float inv = 1.f / sum;
                #pragma unroll
                for (int ni = 0; ni < 4; ni++)
                    Pw[(mi * 16 + quad * 4 + i) * 64 + ni * 16 + l15] =
                        f2b(S[mi][ni][i] * inv);
            }
        }
        __syncthreads();

        short8 bv[4][2];
        #pragma unroll
        for (int ni = 0; ni < 4; ni++)
            #pragma unroll
            for (int kt = 0; kt < 2; kt++)
                bv[ni][kt] = *(const short8*)(vh + (size_t)(ni * 16 + l15) * kD
                                              + kt * 32 + quad * 8);
        short8 pa[4][2];
        #pragma unroll
        for (int mi = 0; mi < 4; mi++)
            #pragma unroll
            for (int kt = 0; kt < 2; kt++)
                pa[mi][kt] = *(const short8*)&Pw[(mi * 16 + l15) * 64
                                                 + kt * 32 + quad * 8];
        f32x4 O[4][4];
        #pragma unroll
        for (int mi = 0; mi < 4; mi++)
            #pragma unroll
            for (int ni = 0; ni < 4; ni++)
                O[mi][ni] = (f32x4){0.f, 0.f, 0.f, 0.f};
        #pragma unroll
        for (int mi = 0; mi < 4; mi++)
            #pragma unroll
            for (int ni = 0; ni < 4; ni++) {
                O[mi][ni] = __builtin_amdgcn_mfma_f32_16x16x32_bf16(
                    pa[mi][0], bv[ni][0], O[mi][ni], 0, 0, 0);
                O[mi][ni] = __builtin_amdgcn_mfma_f32_16x16x32_bf16(
                    pa[mi][1], bv[ni][1], O[mi][ni], 0, 0, 0);
            }
        u16* qo = qbuf + base + h * 64;
        #pragma unroll
        for (int mi = 0; mi < 4; mi++)
            #pragma unroll
            for (int ni = 0; ni < 4; ni++)
                #pragma unroll
                for (int i = 0; i < 4; i++)
                    qo[(size_t)(mi * 16 + quad * 4 + i) * kD + ni * 16 + l15] =
                        f2b(O[mi][ni][i]);
        __syncthreads();
    }
}

// ---------------------------------------------------------------------------
// Row LayerNorm over D=512, bf16 in/out, in-place safe. 4 rows per block.
// ---------------------------------------------------------------------------
__global__ __launch_bounds__(256) void ln_kernel(
    const u16* __restrict__ x, const float* __restrict__ g,
    const float* __restrict__ bb, u16* __restrict__ y)
{
    size_t row = (size_t)blockIdx.x * 4 + (threadIdx.x >> 6);
    int lane = threadIdx.x & 63;
    float v[8];
    float s = 0.f;
    #pragma unroll
    for (int i = 0; i < 8; i++) {
        v[i] = b2f(x[row * kD + lane + i * 64]);
        s += v[i];
    }
    #pragma unroll
    for (int off = 32; off; off >>= 1) s += __shfl_xor(s, off);
    float mean = s * (1.f / kD);
    float sq = 0.f;
    #pragma unroll
    for (int i = 0; i < 8; i++) { float d = v[i] - mean; sq += d * d; }
    #pragma unroll
    for (int off = 32; off; off >>= 1) sq += __shfl_xor(sq, off);
    float inv = 1.f / sqrtf(sq * (1.f / kD) + 1e-5f);
    #pragma unroll
    for (int i = 0; i < 8; i++) {
        int d = lane + i * 64;
        y[row * kD + d] = f2b((v[i] - mean) * inv * g[d] + bb[d]);
    }
}

// ---------------------------------------------------------------------------
// BatchNorm pieces
// ---------------------------------------------------------------------------
__global__ void zero_kernel(float* __restrict__ p, int n)
{
    int i = blockIdx.x * blockDim.x + threadIdx.x;
    if (i < n) p[i] = 0.f;
}

__global__ __launch_bounds__(512) void bn_stats_kernel(
    const u16* __restrict__ tok, float* __restrict__ sums, float* __restrict__ sumsq)
{
    int d = threadIdx.x;
    float s = 0.f, sq = 0.f;
    int row0 = blockIdx.x * 256;
    for (int row = row0; row < row0 + 256; row++) {
        float v = b2f(tok[(size_t)row * kD + d]);
        s += v; sq += v * v;
    }
    atomicAdd(&sums[d], s);
    atomicAdd(&sumsq[d], sq);
}

__global__ __launch_bounds__(512) void bn_final_kernel(
    const float* __restrict__ sums, const float* __restrict__ sumsq,
    const float* __restrict__ g, const float* __restrict__ bb,
    float* __restrict__ scale, float* __restrict__ shift)
{
    int d = threadIdx.x;
    float mean = sums[d] / (float)kM;
    float var = sumsq[d] / (float)kM - mean * mean;
    float sc = g[d] / sqrtf(var + 1e-5f);
    scale[d] = sc;
    shift[d] = bb[d] - mean * sc;
}

// shiftW[t] = sum_r bn_shift[r>>6] * W_head[r*512 + t]  (BN shift folded
// through the head matmul; replaces the 128MB bn_apply pass).  grid 64x512.
__global__ __launch_bounds__(512) void head_shift_kernel(
    const float* __restrict__ W_head, const float* __restrict__ shift,
    float* __restrict__ shiftW)
{
    int t = threadIdx.x;
    int r0 = blockIdx.x * 512;
    float s = 0.f;
    for (int r = r0; r < r0 + 512; r++)
        s += shift[r >> 6] * W_head[(size_t)r * 512 + t];
    atomicAdd(&shiftW[t], s);
}

// reduce split-K head partials (z=16) + biases + instance-denorm:
// out[(b*T+t)*C+c] = (sum_z part + shiftW[t] + b_head[t])*stdev[r] + means[r]
__global__ __launch_bounds__(256) void head_reduce_kernel(
    const float* __restrict__ part, const float* __restrict__ b_head,
    const float* __restrict__ shiftW,
    const float* __restrict__ stdev, const float* __restrict__ means,
    float* __restrict__ out)
{
    int j = blockIdx.x * 256 + threadIdx.x;      // [0, 1024*512)
    int r = j >> 9, t = j & 511;
    float s = 0.f;
    #pragma unroll
    for (int z = 0; z < 16; z++) s += part[((size_t)z << 19) + j];
    int b = r >> 5, c = r & 31;
    out[(((size_t)b * kT + t) << 5) + c] =
        (s + shiftW[t] + b_head[t]) * stdev[r] + means[r];
}

// ---------------------------------------------------------------------------
// Launch
// ---------------------------------------------------------------------------
extern "C" void kernel_launch(void* const* d_in, const int* in_sizes, int n_in,
                              void* d_out, int out_size, void* d_ws, size_t ws_size,
                              hipStream_t stream)
{
    const float* x_enc  = (const float*)d_in[0];
    const float* W_val  = (const float*)d_in[1];
    const float* Wq     = (const float*)d_in[2];
    const float* bq     = (const float*)d_in[3];
    const float* Wk     = (const float*)d_in[4];
    const float* bk     = (const float*)d_in[5];
    const float* Wv     = (const float*)d_in[6];
    const float* bv     = (const float*)d_in[7];
    const float* Wo     = (const float*)d_in[8];
    const float* bo     = (const float*)d_in[9];
    const float* Wc1    = (const float*)d_in[10];
    const float* bc1    = (const float*)d_in[11];
    const float* Wc2    = (const float*)d_in[12];
    const float* bc2    = (const float*)d_in[13];
    const float* ln1_g  = (const float*)d_in[14];
    const float* ln1_b  = (const float*)d_in[15];
    const float* ln2_g  = (const float*)d_in[16];
    const float* ln2_b  = (const float*)d_in[17];
    const float* bn_g   = (const float*)d_in[18];
    const float* bn_b   = (const float*)d_in[19];
    const float* W_head = (const float*)d_in[20];
    const float* b_head = (const float*)d_in[21];
    float* out = (float*)d_out;

    // --- adaptive chunk size: largest CH with tok + 3 units + weights fitting
    const size_t tailBytes = (2 * kR + 5 * kD + 64 * kD) * sizeof(float);
    const size_t headWb = (size_t)512 * 32768;   // W_head bf16 overlay elems
    int CH = 0; size_t unit = 0, region = 0;
    const int cands[4] = {1024, 512, 256, 128};
    for (int ci = 0; ci < 4; ci++) {
        size_t u = (size_t)cands[ci] * 64 * kD;
        size_t reg = 3 * u + kWbElems;
        if (reg < headWb) reg = headWb;
        size_t need = ((size_t)kM * kD + reg) * 2 + tailBytes;
        if (need <= ws_size) { CH = cands[ci]; unit = u; region = reg; break; }
    }
    if (CH == 0) {
        hipLaunchKernelGGL(fill_kernel, dim3((out_size + 255) / 256), dim3(256), 0,
                           stream, out, 1.0e6f, out_size);
        return;
    }
    const int nch = kR / CH;
    const int chRows = CH * 64;

    u16* tokb = (u16*)d_ws;
    u16* s0  = tokb + (size_t)kM * kD;
    u16* s1  = s0 + unit;
    u16* s2  = s1 + unit;
    u16* wbL = s2 + unit;
    u16* wbH = s0;
    u16* wQKV = wbL;                       // [1536][512]
    u16* wO   = wQKV + (size_t)1536 * 512; // [512][512]
    u16* wC1  = wO + (size_t)512 * 512;    // [2048][512]
    u16* wC2  = wC1 + (size_t)2048 * 512;  // [512][2048]
    float* tail = (float*)(s0 + region);
    float* means    = tail;
    float* stdevp   = means + kR;
    float* bn_sums  = stdevp + kR;
    float* bn_sumsq = bn_sums + kD;
    float* shiftW   = bn_sumsq + kD;
    float* bn_scale = shiftW + kD;
    float* bn_shift = bn_scale + kD;
    float* peT      = bn_shift + kD;       // [64][512]

    hipLaunchKernelGGL(pe_kernel, dim3(128), dim3(256), 0, stream, peT);
    hipLaunchKernelGGL(instnorm_stats_kernel, dim3(kB), dim3(256), 0, stream,
                       x_enc, means, stdevp);
    hipLaunchKernelGGL(patch_embed_kernel, dim3(kM), dim3(256), 0, stream,
                       x_enc, W_val, means, stdevp, peT, tokb);

    const dim3 blk(256);
    const int mt = chRows / 128;   // 128-row M tiles per chunk

    for (int i = 0; i < kNL; i++) {
        const float* Wq_i = Wq + (size_t)i * kD * kD;
        const float* Wk_i = Wk + (size_t)i * kD * kD;
        const float* Wv_i = Wv + (size_t)i * kD * kD;
        const float* Wo_i = Wo + (size_t)i * kD * kD;
        const float* Wc1_i = Wc1 + (size_t)i * kD * kDFF;
        const float* Wc2_i = Wc2 + (size_t)i * kDFF * kD;
        const float* bq_i = bq + i * kD, *bk_i = bk + i * kD, *bv_i = bv + i * kD;

        hipLaunchKernelGGL(transpose_cvt4_kernel, dim3(8, 8, 4), blk, 0, stream,
                           Wq_i, Wk_i, Wv_i, Wo_i, wQKV, wO);
        hipLaunchKernelGGL(transpose_cvt_kernel, dim3(8, 32, 1), blk, 0, stream,
                           Wc1_i, wC1, nullptr, kDFF, kD, 0, 0);
        hipLaunchKernelGGL(transpose_cvt_kernel, dim3(32, 8, 1), blk, 0, stream,
                           Wc2_i, wC2, nullptr, kD, kDFF, 0, 0);

        for (int ch = 0; ch < nch; ch++) {
            u16* tokc = tokb + (size_t)ch * chRows * kD;
            // fused QKV: N=1536, routed to s0/s1/s2
            hipLaunchKernelGGL(gemm_qkv, dim3(12, mt, 1), blk, 0, stream,
                               tokc, wQKV, bq_i, bk_i, bv_i, s0, s1, s2,
                               nullptr, kD, kD, kD, kD);
            // transpose V head-tiles in place -> vectorized PV loads
            hipLaunchKernelGGL(vtr_kernel, dim3(CH * 2), blk, 0, stream, s2);
            hipLaunchKernelGGL(attn_mfma_kernel, dim3(CH), blk, 0, stream,
                               s0, s1, s2);
            // tok += attn_out @ Wo + bo
            hipLaunchKernelGGL(gemm_resid, dim3(4, mt, 1), blk, 0, stream,
                               s0, wO, bo + i * kD, nullptr, nullptr,
                               tokc, nullptr, nullptr, nullptr,
                               kD, kD, kD, kD);
            // y = LN1(tok) -> s0
            hipLaunchKernelGGL(ln_kernel, dim3(chRows / 4), blk, 0, stream,
                               tokc, ln1_g + i * kD, ln1_b + i * kD, s0);
            // FFN in two DFF/2 halves; h lives in s1 (per half)
            for (int half = 0; half < 2; half++) {
                const u16* wc1h = wC1 + (size_t)half * 1024 * 512;
                const u16* wc2h = wC2 + (size_t)half * 1024;   // k-offset
                const float* bc1h = bc1 + (size_t)i * kDFF + half * 1024;
                hipLaunchKernelGGL(gemm_gelu, dim3(8, mt, 1), blk, 0, stream,
                                   s0, wc1h, bc1h, nullptr, nullptr,
                                   s1, nullptr, nullptr, nullptr,
                                   kD, kD, kD, 1024);
                hipLaunchKernelGGL(gemm_resid, dim3(4, mt, 1), blk, 0, stream,
                                   s1, wc2h, (half == 0) ? (bc2 + i * kD) : nullptr,
                                   nullptr, nullptr, tokc, nullptr, nullptr,
                                   nullptr, 1024, 1024, kDFF, kD);
            }
            // tok = LN2(tok) in place
            hipLaunchKernelGGL(ln_kernel, dim3(chRows / 4), blk, 0, stream,
                               tokc, ln2_g + i * kD, ln2_b + i * kD, tokc);
        }
    }

    // BatchNorm: stats -> scale/shift; scale folded into W_head transpose,
    // shift folded into shiftW (no bn_apply pass over tok).
    hipLaunchKernelGGL(zero_kernel, dim3(6), dim3(256), 0, stream, bn_sums, 3 * kD);
    hipLaunchKernelGGL(bn_stats_kernel, dim3(kM / 256), dim3(512), 0, stream,
                       tokb, bn_sums, bn_sumsq);
    hipLaunchKernelGGL(bn_final_kernel, dim3(1), dim3(512), 0, stream,
                       bn_sums, bn_sumsq, bn_g, bn_b, bn_scale, bn_shift);
    hipLaunchKernelGGL(head_shift_kernel, dim3(64), dim3(512), 0, stream,
                       W_head, bn_shift, shiftW);

    // head weights: wbH[t][n*512+d] = W_head[(d*64+n)*512+t] * bn_scale[d]
    hipLaunchKernelGGL(transpose_cvt_kernel, dim3(8, 8, 64), blk, 0, stream,
                       W_head, wbH, bn_scale, 64 * 512, 32768, 512, 512);
    // split-K z=16 (2 blocks/CU): disjoint fp32 partials into s1, then reduce
    hipLaunchKernelGGL(gemm_head, dim3(4, 8, 16), blk, 0, stream,
                       tokb, wbH, nullptr, nullptr, nullptr,
                       nullptr, nullptr, nullptr, (float*)s1,
                       2048, 32768, 32768, kT);
    hipLaunchKernelGGL(head_reduce_kernel, dim3(kR * kT / 256), blk, 0, stream,
                       (const float*)s1, b_head, shiftW, stdevp, means, out);
}

// Round 8
// 3185.736 us; speedup vs baseline: 1.0925x; 1.0088x over previous
//
#include <hip/hip_runtime.h>
#include <math.h>

// ---------------------------------------------------------------------------
// Problem constants (PatchTST-style transformer)
// ---------------------------------------------------------------------------
namespace {
constexpr int kB = 32, kT = 512, kC = 32, kD = 512, kDFF = 2048, kNL = 3;
constexpr int kP = 16, kStride = 8, kN = 64;
constexpr int kR = kB * kC;      // 1024 independent (b,c) series
constexpr int kM = kR * kN;      // 65536 tokens total
constexpr size_t kWbElems = (size_t)1536 * 512 + 512 * 512 + 2048 * 512 + 512 * 2048;
}

typedef unsigned short u16;
typedef __attribute__((ext_vector_type(8))) short short8;   // 8 bf16 (4 VGPRs)
typedef __attribute__((ext_vector_type(4))) float f32x4;    // MFMA accumulator

__device__ __forceinline__ float b2f(u16 u) {
    return __uint_as_float(((unsigned int)u) << 16);
}
__device__ __forceinline__ u16 f2b(float f) {
    unsigned int x = __float_as_uint(f);
    return (u16)((x + 0x7fffu + ((x >> 16) & 1u)) >> 16);
}

// async global->LDS, 16B per lane (builtin: IR-visible, __syncthreads-safe).
__device__ __forceinline__ void async_copy16(const u16* g, u16* l) {
    __builtin_amdgcn_global_load_lds(
        (const __attribute__((address_space(1))) unsigned int*)g,
        (__attribute__((address_space(3))) unsigned int*)l, 16, 0, 0);
}

// ---------------------------------------------------------------------------
// Sentinel fill (workspace-too-small diagnostic)
// ---------------------------------------------------------------------------
__global__ void fill_kernel(float* __restrict__ p, float val, int n)
{
    int i = blockIdx.x * blockDim.x + threadIdx.x;
    if (i < n) p[i] = val;
}

// ---------------------------------------------------------------------------
// Instance-norm stats per (b,c)
// ---------------------------------------------------------------------------
__global__ __launch_bounds__(256) void instnorm_stats_kernel(
    const float* __restrict__ x, float* __restrict__ means, float* __restrict__ stdev)
{
    int b = blockIdx.x;
    int c = threadIdx.x & 31;
    int g = threadIdx.x >> 5;
    float s = 0.f, sq = 0.f;
    for (int t = g; t < kT; t += 8) {
        float v = x[(size_t)(b * kT + t) * kC + c];
        s += v; sq += v * v;
    }
    __shared__ float ss[8][32], ssq[8][32];
    ss[g][c] = s; ssq[g][c] = sq;
    __syncthreads();
    if (g == 0) {
        float S = 0.f, SQ = 0.f;
        for (int i = 0; i < 8; i++) { S += ss[i][c]; SQ += ssq[i][c]; }
        float m = S / kT;
        float var = SQ / kT - m * m;
        means[b * kC + c] = m;
        stdev[b * kC + c] = sqrtf(var + 1e-5f);
    }
}

// ---------------------------------------------------------------------------
// Sinusoidal PE table [64][512], computed ONCE (32K transcendentals instead
// of 33.5M in patch_embed)
// ---------------------------------------------------------------------------
__global__ __launch_bounds__(256) void pe_kernel(float* __restrict__ pe)
{
    int i = blockIdx.x * 256 + threadIdx.x;    // [0, 32768)
    int n = i >> 9, d = i & 511;
    int j = d >> 1;
    float freq = expf(-(float)(2 * j) * (9.210340371976184f / (float)kD));
    float ang = (float)n * freq;
    pe[i] = (d & 1) ? cosf(ang) : sinf(ang);
}

// ---------------------------------------------------------------------------
// Patch embed, one block PER SERIES (R7 diagnosis: 65536 tiny blocks were
// launch/latency-bound at 85us, VALUBusy 47%, HBM 10%).  Stage normalized
// series (512+pad) and all of W_val (32KB fp32) in LDS once; each thread
// emits 128 outputs (16 patches x 8 contiguous d) with wave-uniform xn
// broadcasts, contiguous 32B wv reads, and short8 vector stores.
// ---------------------------------------------------------------------------
__global__ __launch_bounds__(256) void patch_embed_kernel(
    const float* __restrict__ x, const float* __restrict__ Wval,
    const float* __restrict__ means, const float* __restrict__ stdev,
    const float* __restrict__ pe, u16* __restrict__ tok)
{
    __shared__ float xn[kT + 16];
    __shared__ float wv[kP * kD];          // 32 KB
    const int r = blockIdx.x;              // series = b*32 + c
    const int b = r >> 5, c = r & 31;
    const int tid = threadIdx.x;
    const float mean = means[r], inv = 1.f / stdev[r];
    for (int t = tid; t < kT; t += 256)
        xn[t] = (x[(size_t)(b * kT + t) * kC + c] - mean) * inv;
    if (tid < 16)   // replication pad (read x directly; no LDS dependency)
        xn[kT + tid] = (x[(size_t)(b * kT + kT - 1) * kC + c] - mean) * inv;
    for (int i = tid * 4; i < kP * kD; i += 1024)
        *(float4*)&wv[i] = *(const float4*)&Wval[i];
    __syncthreads();

    const int lane = tid & 63, w = tid >> 6;
    const int d0 = lane << 3;
    for (int g = 0; g < 16; g++) {
        const int n = g * 4 + w;
        const float* pen = pe + (size_t)n * kD + d0;
        float acc[8];
        #pragma unroll
        for (int j = 0; j < 8; j++) acc[j] = pen[j];
        #pragma unroll
        for (int p = 0; p < kP; p++) {
            float xv = xn[n * kStride + p];          // wave-uniform broadcast
            const float* wp = &wv[p * kD + d0];      // 32B contiguous
            #pragma unroll
            for (int j = 0; j < 8; j++) acc[j] += xv * wp[j];
        }
        short8 o;
        #pragma unroll
        for (int j = 0; j < 8; j++) o[j] = (short)f2b(acc[j]);
        *(short8*)&tok[((size_t)r * 64 + n) * kD + d0] = o;
    }
}

// ---------------------------------------------------------------------------
// Transpose + fp32->bf16 convert: out[n*ldo + k] = f2b(in[k*ldi + n] * sc[k])
// per z-slice: in += z*zin, out += z*zout.  grid (K/64, N/64, Z), 256 thr.
// scale==nullptr -> 1.0 (scale indexed by the kernel's k dim; for the head
// call k == d, so passing bn_scale folds BatchNorm's scale into W_head).
// ---------------------------------------------------------------------------
__global__ __launch_bounds__(256) void transpose_cvt_kernel(
    const float* __restrict__ in, u16* __restrict__ outp,
    const float* __restrict__ scale,
    int ldi, int ldo, int zin, int zout)
{
    __shared__ float tile[64][65];
    const float* ib = in + (size_t)blockIdx.z * zin;
    u16* ob = outp + (size_t)blockIdx.z * zout;
    int k0 = blockIdx.x * 64, n0 = blockIdx.y * 64;
    int tn = threadIdx.x & 63, tk0 = threadIdx.x >> 6;
    #pragma unroll
    for (int kk = tk0; kk < 64; kk += 4) {
        float sc = scale ? scale[k0 + kk] : 1.f;
        tile[kk][tn] = ib[(size_t)(k0 + kk) * ldi + n0 + tn] * sc;
    }
    __syncthreads();
    int wk = threadIdx.x & 63, wn0 = threadIdx.x >> 6;
    #pragma unroll
    for (int nn = wn0; nn < 64; nn += 4)
        ob[(size_t)(n0 + nn) * ldo + k0 + wk] = f2b(tile[wk][nn]);
}

// Batched 512x512 transposes for Wq/Wk/Wv/Wo (one launch instead of four).
// z=0..2 -> wQKV + z*256K; z=3 -> wO.  grid (8, 8, 4).
__global__ __launch_bounds__(256) void transpose_cvt4_kernel(
    const float* __restrict__ in0, const float* __restrict__ in1,
    const float* __restrict__ in2, const float* __restrict__ in3,
    u16* __restrict__ outQKV, u16* __restrict__ outO)
{
    __shared__ float tile[64][65];
    int z = blockIdx.z;
    const float* ib = (z == 0) ? in0 : (z == 1) ? in1 : (z == 2) ? in2 : in3;
    u16* ob = (z < 3) ? outQKV + (size_t)z * 512 * 512 : outO;
    int k0 = blockIdx.x * 64, n0 = blockIdx.y * 64;
    int tn = threadIdx.x & 63, tk0 = threadIdx.x >> 6;
    #pragma unroll
    for (int kk = tk0; kk < 64; kk += 4)
        tile[kk][tn] = ib[(size_t)(k0 + kk) * 512 + n0 + tn];
    __syncthreads();
    int wk = threadIdx.x & 63, wn0 = threadIdx.x >> 6;
    #pragma unroll
    for (int nn = wn0; nn < 64; nn += 4)
        ob[(size_t)(n0 + nn) * 512 + k0 + wk] = f2b(tile[wk][nn]);
}

// ---------------------------------------------------------------------------
// MFMA bf16 GEMM core, 128x128 tile, BK=64, 256 thr (4 waves 2x2), m97
// structure.  R5-verified: 0 bank conflicts, head-class 147->128 us vs R0.
// LDS 32 KiB; chunk-XOR swizzle p^(r&7); global src pre-swizzled.
// A: [M][lda] bf16 row-major.  B: [N][ldb] bf16 N-MAJOR (row n = output col).
// grid: (N/128, M/128, Z) — Z>1 = split-K (global k = z*K + kb), EPI 3 only.
// EPI 0: qkv   EPI 1: bf16 rmw +bias   EPI 2: gelu   EPI 3: fp32 partials
// ---------------------------------------------------------------------------
template<int EPI>
__device__ __forceinline__ void gemm_body(
    const u16* __restrict__ A, const u16* __restrict__ B,
    const float* __restrict__ bias, const float* __restrict__ auxb1,
    const float* __restrict__ auxb2,
    u16* __restrict__ C0, u16* __restrict__ C1, u16* __restrict__ C2,
    float* __restrict__ fout,
    int K, int lda, int ldb, int ldc)
{
    __shared__ alignas(16) u16 As[128 * 64];   // 16 KiB
    __shared__ alignas(16) u16 Bs[128 * 64];   // 16 KiB

    const int tid  = threadIdx.x;
    const int lane = tid & 63;
    const int wave = tid >> 6;
    const int wm   = wave >> 1;        // 0..1
    const int wn   = wave & 1;         // 0..1

    // bijective XCD swizzle (m204) over the (x,y) grid plane
    const int nwg  = gridDim.x * gridDim.y;
    const int orig = blockIdx.y * gridDim.x + blockIdx.x;
    const int qq = nwg >> 3, rr = nwg & 7;
    const int xcd = orig & 7, loc = orig >> 3;
    const int wg  = (xcd < rr) ? (xcd * (qq + 1) + loc)
                               : (rr * (qq + 1) + (xcd - rr) * qq + loc);
    const int row0 = (wg / gridDim.x) * 128;
    const int col0 = (wg % gridDim.x) * 128;
    const size_t zoff = (size_t)blockIdx.z * K;

    // staging: 8 lanes/row (8x16B = 128B row), 32 rows per async round,
    // 4 rounds per matrix.  Lane fetches logical chunk (tid&7)^(srow&7) so
    // the linear DMA dest (base + tid*16B) yields phys chunk p = q^(r&7).
    const int srow = tid >> 3;                         // 0..31
    const int scol = (((tid & 7) ^ (srow & 7)) << 3);
    const u16* const Ag = A + (size_t)(row0 + srow) * lda + zoff + scol;
    const u16* const Bg = B + (size_t)(col0 + srow) * ldb + zoff + scol;
    u16* const AsW = As + (wave << 9);   // this wave's 8-row piece per round
    u16* const BsW = Bs + (wave << 9);

    // fragment reads: logical chunk q (=lane>>4 for k-half 0; ^4 for half 1)
    // of row r sits at phys q^(r&7); r&7 == lane&7 within each 16-row group.
    const int fr = lane & 15;
    const int pc = (lane >> 4) ^ (lane & 7);
    const int a0 = ((wm << 6) + fr) * 64 + (pc << 3);
    const int a1 = ((wm << 6) + fr) * 64 + ((pc ^ 4) << 3);
    const int b0 = ((wn << 6) + fr) * 64 + (pc << 3);
    const int b1 = ((wn << 6) + fr) * 64 + ((pc ^ 4) << 3);

    short8 af[4], bfr[4];
    f32x4 acc[4][4];
    #pragma unroll
    for (int i = 0; i < 4; i++)
        #pragma unroll
        for (int j = 0; j < 4; j++)
            acc[i][j] = (f32x4){0.f, 0.f, 0.f, 0.f};

    for (int kb = 0; kb < K; kb += 64) {
        __syncthreads();
        #pragma unroll
        for (int c = 0; c < 4; c++) {
            async_copy16(Ag + kb + (size_t)(c * 32) * lda, AsW + c * 2048);
            async_copy16(Bg + kb + (size_t)(c * 32) * ldb, BsW + c * 2048);
        }
        __syncthreads();
        // k-half 0
        #pragma unroll
        for (int mi = 0; mi < 4; mi++) af[mi]  = *(const short8*)&As[a0 + (mi << 10)];
        #pragma unroll
        for (int ni = 0; ni < 4; ni++) bfr[ni] = *(const short8*)&Bs[b0 + (ni << 10)];
        #pragma unroll
        for (int mi = 0; mi < 4; mi++)
            #pragma unroll
            for (int ni = 0; ni < 4; ni++)
                acc[mi][ni] = __builtin_amdgcn_mfma_f32_16x16x32_bf16(
                    af[mi], bfr[ni], acc[mi][ni], 0, 0, 0);
        // k-half 1
        #pragma unroll
        for (int mi = 0; mi < 4; mi++) af[mi]  = *(const short8*)&As[a1 + (mi << 10)];
        #pragma unroll
        for (int ni = 0; ni < 4; ni++) bfr[ni] = *(const short8*)&Bs[b1 + (ni << 10)];
        #pragma unroll
        for (int mi = 0; mi < 4; mi++)
            #pragma unroll
            for (int ni = 0; ni < 4; ni++)
                acc[mi][ni] = __builtin_amdgcn_mfma_f32_16x16x32_bf16(
                    af[mi], bfr[ni], acc[mi][ni], 0, 0, 0);
    }

    // epilogue: C/D layout col=lane&15, row=(lane>>4)*4+i  [m89-verified]
    const int er = (lane >> 4) << 2;
    const int ec = lane & 15;
    u16* dsel = C0;
    const float* bsel = bias;
    if (EPI == 0) {
        int sub = col0 >> 9;
        dsel = (sub == 0) ? C0 : ((sub == 1) ? C1 : C2);
        bsel = (sub == 0) ? bias : ((sub == 1) ? auxb1 : auxb2);
    }
    #pragma unroll
    for (int mi = 0; mi < 4; mi++) {
        #pragma unroll
        for (int ni = 0; ni < 4; ni++) {
            #pragma unroll
            for (int i = 0; i < 4; i++) {
                int r  = row0 + (wm << 6) + (mi << 4) + er + i;
                int cc = col0 + (wn << 6) + (ni << 4) + ec;
                float v = acc[mi][ni][i];
                if (EPI == 0) {
                    int cl = cc & 511;
                    dsel[(size_t)r * 512 + cl] = f2b(v + bsel[cl]);
                } else if (EPI == 1) {
                    size_t o = (size_t)r * ldc + cc;
                    float bb2 = bias ? bias[cc] : 0.f;
                    C0[o] = f2b(b2f(C0[o]) + v + bb2);
                } else if (EPI == 2) {
                    size_t o = (size_t)r * ldc + cc;
                    float z = v + bias[cc];
                    C0[o] = f2b(0.5f * z * (1.f + erff(z * 0.7071067811865475f)));
                } else {
                    // disjoint fp32 partials per z-slice (no atomics)
                    fout[((size_t)blockIdx.z << 19) + (size_t)r * ldc + cc] = v;
                }
            }
        }
    }
}

#define GEMM_ARGS \
    const u16* __restrict__ A, const u16* __restrict__ B, \
    const float* __restrict__ bias, const float* __restrict__ auxb1, \
    const float* __restrict__ auxb2, \
    u16* __restrict__ C0, u16* __restrict__ C1, u16* __restrict__ C2, \
    float* __restrict__ fout, \
    int K, int lda, int ldb, int ldc
#define GEMM_PASS A, B, bias, auxb1, auxb2, C0, C1, C2, fout, K, lda, ldb, ldc

__global__ __launch_bounds__(256) void gemm_qkv(GEMM_ARGS)   { gemm_body<0>(GEMM_PASS); }
__global__ __launch_bounds__(256) void gemm_resid(GEMM_ARGS) { gemm_body<1>(GEMM_PASS); }
__global__ __launch_bounds__(256) void gemm_gelu(GEMM_ARGS)  { gemm_body<2>(GEMM_PASS); }
__global__ __launch_bounds__(256) void gemm_head(GEMM_ARGS)  { gemm_body<3>(GEMM_PASS); }

// ---------------------------------------------------------------------------
// Batched in-place 64x64 transpose of V head-tiles:
//   v[series*64 + n][h*64 + e]  ->  v[series*64 + e][h*64 + n]
// so attention's PV B-operand becomes a vectorized b128 row load.
// ---------------------------------------------------------------------------
__global__ __launch_bounds__(256) void vtr_kernel(u16* __restrict__ v)
{
    __shared__ u16 tl[4][64 * 72];
    const int tid = threadIdx.x;
    const int wave = tid >> 6, lane = tid & 63;
    const int sr = lane >> 3, ch = lane & 7;
    const int tile = blockIdx.x * 4 + wave;
    const int series = tile >> 3, h = tile & 7;
    u16* g = v + (size_t)series * 64 * kD + h * 64;
    u16* T = tl[wave];
    short8 rd[8];
    #pragma unroll
    for (int r = 0; r < 8; r++)
        rd[r] = *(const short8*)(g + (size_t)(r * 8 + sr) * kD + ch * 8);
    #pragma unroll
    for (int r = 0; r < 8; r++)
        *(short8*)&T[(r * 8 + sr) * 72 + ch * 8] = rd[r];
    __syncthreads();
    #pragma unroll
    for (int r = 0; r < 8; r++) {
        short8 wr;
        #pragma unroll
        for (int q = 0; q < 8; q++)
            wr[q] = (short)T[(ch * 8 + q) * 72 + (r * 8 + sr)];
        *(short8*)(g + (size_t)(r * 8 + sr) * kD + ch * 8) = wr;
    }
}

// ---------------------------------------------------------------------------
// MFMA attention. One block per series; 4 waves; wave w does heads 2w, 2w+1.
// q,k: bf16 [rows=64*series][512]; v PRE-TRANSPOSED per head-tile (vtr).
// Output in place over q.
// ---------------------------------------------------------------------------
__global__ __launch_bounds__(256) void attn_mfma_kernel(
    u16* __restrict__ qbuf, const u16* __restrict__ kbuf,
    const u16* __restrict__ vbuf)
{
    __shared__ u16 P[4][64 * 64];   // 8 KB per wave
    const int tid = threadIdx.x;
    const int wave = tid >> 6, lane = tid & 63;
    const int quad = lane >> 4, l15 = lane & 15;
    const size_t base = (size_t)blockIdx.x * 64 * kD;
    u16* Pw = P[wave];

    for (int hh = 0; hh < 2; hh++) {
        const int h = wave * 2 + hh;
        const u16* qh = qbuf + base + h * 64;
        const u16* kh = kbuf + base + h * 64;
        const u16* vh = vbuf + base + h * 64;

        short8 af[4][2], bf[4][2];
        #pragma unroll
        for (int mi = 0; mi < 4; mi++)
            #pragma unroll
            for (int kt = 0; kt < 2; kt++)
                af[mi][kt] = *(const short8*)(qh + (size_t)(mi * 16 + l15) * kD
                                              + kt * 32 + quad * 8);
        #pragma unroll
        for (int ni = 0; ni < 4; ni++)
            #pragma unroll
            for (int kt = 0; kt < 2; kt++)
                bf[ni][kt] = *(const short8*)(kh + (size_t)(ni * 16 + l15) * kD
                                              + kt * 32 + quad * 8);
        f32x4 S[4][4];
        #pragma unroll
        for (int mi = 0; mi < 4; mi++)
            #pragma unroll
            for (int ni = 0; ni < 4; ni++)
                S[mi][ni] = (f32x4){0.f, 0.f, 0.f, 0.f};
        #pragma unroll
        for (int mi = 0; mi < 4; mi++)
            #pragma unroll
            for (int ni = 0; ni < 4; ni++) {
                S[mi][ni] = __builtin_amdgcn_mfma_f32_16x16x32_bf16(
                    af[mi][0], bf[ni][0], S[mi][ni], 0, 0, 0);
                S[mi][ni] = __builtin_amdgcn_mfma_f32_16x16x32_bf16(
                    af[mi][1], bf[ni][1], S[mi][ni], 0, 0, 0);
            }

        #pragma unroll
        for (int mi = 0; mi < 4; mi++) {
            #pragma unroll
            for (int i = 0; i < 4; i++) {
                float mx = -1e30f;
                #pragma unroll
                for (int ni = 0; ni < 4; ni++) {
                    float v = S[mi][ni][i] * 0.125f;
                    S[mi][ni][i] = v;
                    mx = fmaxf(mx, v);
                }
                #pragma unroll
                for (int off = 1; off < 16; off <<= 1)
                    mx = fmaxf(mx, __shfl_xor(mx, off));
                float sum = 0.f;
                #pragma unroll
                for (int ni = 0; ni < 4; ni++) {
                    float e = expf(S[mi][ni][i] - mx);
                    S[mi][ni][i] = e;
                    sum += e;
                }
                #pragma unroll
                for (int off = 1; off < 16; off <<= 1)
                    sum += __shfl_xor(sum, off);
                float inv = 1.f / sum;
                #pragma unroll
                for (int ni = 0; ni < 4; ni++)
                    Pw[(mi * 16 + quad * 4 + i) * 64 + ni * 16 + l15] =
                        f2b(S[mi][ni][i] * inv);
            }
        }
        __syncthreads();

        short8 bv[4][2];
        #pragma unroll
        for (int ni = 0; ni < 4; ni++)
            #pragma unroll
            for (int kt = 0; kt < 2; kt++)
                bv[ni][kt] = *(const short8*)(vh + (size_t)(ni * 16 + l15) * kD
                                              + kt * 32 + quad * 8);
        short8 pa[4][2];
        #pragma unroll
        for (int mi = 0; mi < 4; mi++)
            #pragma unroll
            for (int kt = 0; kt < 2; kt++)
                pa[mi][kt] = *(const short8*)&Pw[(mi * 16 + l15) * 64
                                                 + kt * 32 + quad * 8];
        f32x4 O[4][4];
        #pragma unroll
        for (int mi = 0; mi < 4; mi++)
            #pragma unroll
            for (int ni = 0; ni < 4; ni++)
                O[mi][ni] = (f32x4){0.f, 0.f, 0.f, 0.f};
        #pragma unroll
        for (int mi = 0; mi < 4; mi++)
            #pragma unroll
            for (int ni = 0; ni < 4; ni++) {
                O[mi][ni] = __builtin_amdgcn_mfma_f32_16x16x32_bf16(
                    pa[mi][0], bv[ni][0], O[mi][ni], 0, 0, 0);
                O[mi][ni] = __builtin_amdgcn_mfma_f32_16x16x32_bf16(
                    pa[mi][1], bv[ni][1], O[mi][ni], 0, 0, 0);
            }
        u16* qo = qbuf + base + h * 64;
        #pragma unroll
        for (int mi = 0; mi < 4; mi++)
            #pragma unroll
            for (int ni = 0; ni < 4; ni++)
                #pragma unroll
                for (int i = 0; i < 4; i++)
                    qo[(size_t)(mi * 16 + quad * 4 + i) * kD + ni * 16 + l15] =
                        f2b(O[mi][ni][i]);
        __syncthreads();
    }
}

// ---------------------------------------------------------------------------
// Row LayerNorm over D=512, bf16 in/out, in-place safe. 4 rows per block.
// Vectorized short8 loads/stores (lane owns 8 consecutive cols).
// ---------------------------------------------------------------------------
__global__ __launch_bounds__(256) void ln_kernel(
    const u16* __restrict__ x, const float* __restrict__ g,
    const float* __restrict__ bb, u16* __restrict__ y)
{
    size_t row = (size_t)blockIdx.x * 4 + (threadIdx.x >> 6);
    int lane = threadIdx.x & 63;
    int d0 = lane << 3;
    short8 xv = *(const short8*)&x[row * kD + d0];
    float v[8];
    float s = 0.f;
    #pragma unroll
    for (int i = 0; i < 8; i++) {
        v[i] = b2f((u16)xv[i]);
        s += v[i];
    }
    #pragma unroll
    for (int off = 32; off; off >>= 1) s += __shfl_xor(s, off);
    float mean = s * (1.f / kD);
    float sq = 0.f;
    #pragma unroll
    for (int i = 0; i < 8; i++) { float d = v[i] - mean; sq += d * d; }
    #pragma unroll
    for (int off = 32; off; off >>= 1) sq += __shfl_xor(sq, off);
    float inv = 1.f / sqrtf(sq * (1.f / kD) + 1e-5f);
    short8 o;
    #pragma unroll
    for (int i = 0; i < 8; i++)
        o[i] = (short)f2b((v[i] - mean) * inv * g[d0 + i] + bb[d0 + i]);
    *(short8*)&y[row * kD + d0] = o;
}

// ---------------------------------------------------------------------------
// BatchNorm pieces
// ---------------------------------------------------------------------------
__global__ void zero_kernel(float* __restrict__ p, int n)
{
    int i = blockIdx.x * blockDim.x + threadIdx.x;
    if (i < n) p[i] = 0.f;
}

__global__ __launch_bounds__(512) void bn_stats_kernel(
    const u16* __restrict__ tok, float* __restrict__ sums, float* __restrict__ sumsq)
{
    int d = threadIdx.x;
    float s = 0.f, sq = 0.f;
    int row0 = blockIdx.x * 256;
    for (int row = row0; row < row0 + 256; row++) {
        float v = b2f(tok[(size_t)row * kD + d]);
        s += v; sq += v * v;
    }
    atomicAdd(&sums[d], s);
    atomicAdd(&sumsq[d], sq);
}

__global__ __launch_bounds__(512) void bn_final_kernel(
    const float* __restrict__ sums, const float* __restrict__ sumsq,
    const float* __restrict__ g, const float* __restrict__ bb,
    float* __restrict__ scale, float* __restrict__ shift)
{
    int d = threadIdx.x;
    float mean = sums[d] / (float)kM;
    float var = sumsq[d] / (float)kM - mean * mean;
    float sc = g[d] / sqrtf(var + 1e-5f);
    scale[d] = sc;
    shift[d] = bb[d] - mean * sc;
}

// shiftW[t] = sum_r bn_shift[r>>6] * W_head[r*512 + t]  (BN shift folded
// through the head matmul; replaces the 128MB bn_apply pass).  grid 64x512.
__global__ __launch_bounds__(512) void head_shift_kernel(
    const float* __restrict__ W_head, const float* __restrict__ shift,
    float* __restrict__ shiftW)
{
    int t = threadIdx.x;
    int r0 = blockIdx.x * 512;
    float s = 0.f;
    for (int r = r0; r < r0 + 512; r++)
        s += shift[r >> 6] * W_head[(size_t)r * 512 + t];
    atomicAdd(&shiftW[t], s);
}

// reduce split-K head partials (z=16) + biases + instance-denorm:
// out[(b*T+t)*C+c] = (sum_z part + shiftW[t] + b_head[t])*stdev[r] + means[r]
__global__ __launch_bounds__(256) void head_reduce_kernel(
    const float* __restrict__ part, const float* __restrict__ b_head,
    const float* __restrict__ shiftW,
    const float* __restrict__ stdev, const float* __restrict__ means,
    float* __restrict__ out)
{
    int j = blockIdx.x * 256 + threadIdx.x;      // [0, 1024*512)
    int r = j >> 9, t = j & 511;
    float s = 0.f;
    #pragma unroll
    for (int z = 0; z < 16; z++) s += part[((size_t)z << 19) + j];
    int b = r >> 5, c = r & 31;
    out[(((size_t)b * kT + t) << 5) + c] =
        (s + shiftW[t] + b_head[t]) * stdev[r] + means[r];
}

// ---------------------------------------------------------------------------
// Launch
// ---------------------------------------------------------------------------
extern "C" void kernel_launch(void* const* d_in, const int* in_sizes, int n_in,
                              void* d_out, int out_size, void* d_ws, size_t ws_size,
                              hipStream_t stream)
{
    const float* x_enc  = (const float*)d_in[0];
    const float* W_val  = (const float*)d_in[1];
    const float* Wq     = (const float*)d_in[2];
    const float* bq     = (const float*)d_in[3];
    const float* Wk     = (const float*)d_in[4];
    const float* bk     = (const float*)d_in[5];
    const float* Wv     = (const float*)d_in[6];
    const float* bv     = (const float*)d_in[7];
    const float* Wo     = (const float*)d_in[8];
    const float* bo     = (const float*)d_in[9];
    const float* Wc1    = (const float*)d_in[10];
    const float* bc1    = (const float*)d_in[11];
    const float* Wc2    = (const float*)d_in[12];
    const float* bc2    = (const float*)d_in[13];
    const float* ln1_g  = (const float*)d_in[14];
    const float* ln1_b  = (const float*)d_in[15];
    const float* ln2_g  = (const float*)d_in[16];
    const float* ln2_b  = (const float*)d_in[17];
    const float* bn_g   = (const float*)d_in[18];
    const float* bn_b   = (const float*)d_in[19];
    const float* W_head = (const float*)d_in[20];
    const float* b_head = (const float*)d_in[21];
    float* out = (float*)d_out;

    // --- adaptive chunk size: largest CH with tok + 3 units + weights fitting
    const size_t tailBytes = (2 * kR + 5 * kD + 64 * kD) * sizeof(float);
    const size_t headWb = (size_t)512 * 32768;   // W_head bf16 overlay elems
    int CH = 0; size_t unit = 0, region = 0;
    const int cands[4] = {1024, 512, 256, 128};
    for (int ci = 0; ci < 4; ci++) {
        size_t u = (size_t)cands[ci] * 64 * kD;
        size_t reg = 3 * u + kWbElems;
        if (reg < headWb) reg = headWb;
        size_t need = ((size_t)kM * kD + reg) * 2 + tailBytes;
        if (need <= ws_size) { CH = cands[ci]; unit = u; region = reg; break; }
    }
    if (CH == 0) {
        hipLaunchKernelGGL(fill_kernel, dim3((out_size + 255) / 256), dim3(256), 0,
                           stream, out, 1.0e6f, out_size);
        return;
    }
    const int nch = kR / CH;
    const int chRows = CH * 64;

    u16* tokb = (u16*)d_ws;
    u16* s0  = tokb + (size_t)kM * kD;
    u16* s1  = s0 + unit;
    u16* s2  = s1 + unit;
    u16* wbL = s2 + unit;
    u16* wbH = s0;
    u16* wQKV = wbL;                       // [1536][512]
    u16* wO   = wQKV + (size_t)1536 * 512; // [512][512]
    u16* wC1  = wO + (size_t)512 * 512;    // [2048][512]
    u16* wC2  = wC1 + (size_t)2048 * 512;  // [512][2048]
    float* tail = (float*)(s0 + region);
    float* means    = tail;
    float* stdevp   = means + kR;
    float* bn_sums  = stdevp + kR;
    float* bn_sumsq = bn_sums + kD;
    float* shiftW   = bn_sumsq + kD;
    float* bn_scale = shiftW + kD;
    float* bn_shift = bn_scale + kD;
    float* peT      = bn_shift + kD;       // [64][512]

    hipLaunchKernelGGL(pe_kernel, dim3(128), dim3(256), 0, stream, peT);
    hipLaunchKernelGGL(instnorm_stats_kernel, dim3(kB), dim3(256), 0, stream,
                       x_enc, means, stdevp);
    hipLaunchKernelGGL(patch_embed_kernel, dim3(kR), dim3(256), 0, stream,
                       x_enc, W_val, means, stdevp, peT, tokb);

    const dim3 blk(256);
    const int mt = chRows / 128;   // 128-row M tiles per chunk

    for (int i = 0; i < kNL; i++) {
        const float* Wq_i = Wq + (size_t)i * kD * kD;
        const float* Wk_i = Wk + (size_t)i * kD * kD;
        const float* Wv_i = Wv + (size_t)i * kD * kD;
        const float* Wo_i = Wo + (size_t)i * kD * kD;
        const float* Wc1_i = Wc1 + (size_t)i * kD * kDFF;
        const float* Wc2_i = Wc2 + (size_t)i * kDFF * kD;
        const float* bq_i = bq + i * kD, *bk_i = bk + i * kD, *bv_i = bv + i * kD;

        hipLaunchKernelGGL(transpose_cvt4_kernel, dim3(8, 8, 4), blk, 0, stream,
                           Wq_i, Wk_i, Wv_i, Wo_i, wQKV, wO);
        hipLaunchKernelGGL(transpose_cvt_kernel, dim3(8, 32, 1), blk, 0, stream,
                           Wc1_i, wC1, nullptr, kDFF, kD, 0, 0);
        hipLaunchKernelGGL(transpose_cvt_kernel, dim3(32, 8, 1), blk, 0, stream,
                           Wc2_i, wC2, nullptr, kD, kDFF, 0, 0);

        for (int ch = 0; ch < nch; ch++) {
            u16* tokc = tokb + (size_t)ch * chRows * kD;
            // fused QKV: N=1536, routed to s0/s1/s2
            hipLaunchKernelGGL(gemm_qkv, dim3(12, mt, 1), blk, 0, stream,
                               tokc, wQKV, bq_i, bk_i, bv_i, s0, s1, s2,
                               nullptr, kD, kD, kD, kD);
            // transpose V head-tiles in place -> vectorized PV loads
            hipLaunchKernelGGL(vtr_kernel, dim3(CH * 2), blk, 0, stream, s2);
            hipLaunchKernelGGL(attn_mfma_kernel, dim3(CH), blk, 0, stream,
                               s0, s1, s2);
            // tok += attn_out @ Wo + bo
            hipLaunchKernelGGL(gemm_resid, dim3(4, mt, 1), blk, 0, stream,
                               s0, wO, bo + i * kD, nullptr, nullptr,
                               tokc, nullptr, nullptr, nullptr,
                               kD, kD, kD, kD);
            // y = LN1(tok) -> s0
            hipLaunchKernelGGL(ln_kernel, dim3(chRows / 4), blk, 0, stream,
                               tokc, ln1_g + i * kD, ln1_b + i * kD, s0);
            // FFN in two DFF/2 halves; h lives in s1 (per half)
            for (int half = 0; half < 2; half++) {
                const u16* wc1h = wC1 + (size_t)half * 1024 * 512;
                const u16* wc2h = wC2 + (size_t)half * 1024;   // k-offset
                const float* bc1h = bc1 + (size_t)i * kDFF + half * 1024;
                hipLaunchKernelGGL(gemm_gelu, dim3(8, mt, 1), blk, 0, stream,
                                   s0, wc1h, bc1h, nullptr, nullptr,
                                   s1, nullptr, nullptr, nullptr,
                                   kD, kD, kD, 1024);
                hipLaunchKernelGGL(gemm_resid, dim3(4, mt, 1), blk, 0, stream,
                                   s1, wc2h, (half == 0) ? (bc2 + i * kD) : nullptr,
                                   nullptr, nullptr, tokc, nullptr, nullptr,
                                   nullptr, 1024, 1024, kDFF, kD);
            }
            // tok = LN2(tok) in place
            hipLaunchKernelGGL(ln_kernel, dim3(chRows / 4), blk, 0, stream,
                               tokc, ln2_g + i * kD, ln2_b + i * kD, tokc);
        }
    }

    // BatchNorm: stats -> scale/shift; scale folded into W_head transpose,
    // shift folded into shiftW (no bn_apply pass over tok).
    hipLaunchKernelGGL(zero_kernel, dim3(6), dim3(256), 0, stream, bn_sums, 3 * kD);
    hipLaunchKernelGGL(bn_stats_kernel, dim3(kM / 256), dim3(512), 0, stream,
                       tokb, bn_sums, bn_sumsq);
    hipLaunchKernelGGL(bn_final_kernel, dim3(1), dim3(512), 0, stream,
                       bn_sums, bn_sumsq, bn_g, bn_b, bn_scale, bn_shift);
    hipLaunchKernelGGL(head_shift_kernel, dim3(64), dim3(512), 0, stream,
                       W_head, bn_shift, shiftW);

    // head weights: wbH[t][n*512+d] = W_head[(d*64+n)*512+t] * bn_scale[d]
    hipLaunchKernelGGL(transpose_cvt_kernel, dim3(8, 8, 64), blk, 0, stream,
                       W_head, wbH, bn_scale, 64 * 512, 32768, 512, 512);
    // split-K z=16 (2 blocks/CU): disjoint fp32 partials into s1, then reduce
    hipLaunchKernelGGL(gemm_head, dim3(4, 8, 16), blk, 0, stream,
                       tokb, wbH, nullptr, nullptr, nullptr,
                       nullptr, nullptr, nullptr, (float*)s1,
                       2048, 32768, 32768, kT);
    hipLaunchKernelGGL(head_reduce_kernel, dim3(kR * kT / 256), blk, 0, stream,
                       (const float*)s1, b_head, shiftW, stdevp, means, out);
}